// Round 1
// baseline (1405.022 us; speedup 1.0000x reference)
//
#include <hip/hip_runtime.h>

typedef __attribute__((ext_vector_type(8))) short short8;
typedef __attribute__((ext_vector_type(4))) float f32x4;
typedef unsigned long long ull;

constexpr int H    = 516;    // hidden
constexpr int GP   = 2080;   // padded gate cols (65*32), permuted chat = 4*u+g
constexpr int KH   = 544;    // padded hidden K (17*32)
constexpr int KE   = 256;    // embedding dim
constexpr int NB   = 65;     // recurrence blocks (8 units each -> 520 padded units)
constexpr int SB   = 32;     // batch
constexpr int SEQ  = 64;
constexpr int MROW = 2048;   // SEQ*SB
constexpr int V    = 32000;
constexpr int NBN  = 250;    // V/128
constexpr int HSROW = 552;   // padded LDS row stride (shorts) -> conflict-free b128

__device__ __forceinline__ float bf2f(short s) {
  unsigned u = ((unsigned)(unsigned short)s) << 16;
  float f; __builtin_memcpy(&f, &u, 4); return f;
}
__device__ __forceinline__ short f2bf(float f) {
  unsigned u; __builtin_memcpy(&u, &f, 4);
  u += 0x7fffu + ((u >> 16) & 1u);
  return (short)(u >> 16);
}
__device__ __forceinline__ float sigm(float x){ return 1.f/(1.f+__expf(-x)); }
__device__ __forceinline__ float tanh_(float x){ float e=__expf(-2.f*x); return (1.f-e)/(1.f+e); }

// ---------------- pack kernels ----------------
__global__ void k_pack_gates(const float* __restrict__ W1, const float* __restrict__ W2,
                             short* __restrict__ dst, int ksteps) {
  int gid = blockIdx.x * 256 + threadIdx.x;
  int total = NB * 2 * ksteps * 64;
  if (gid >= total) return;
  int lane = gid & 63;
  int rest = gid >> 6;
  int ks = rest % ksteps; rest /= ksteps;
  int nt = rest & 1; int bid = rest >> 1;
  int chat = bid * 32 + nt * 16 + (lane & 15);
  int u = chat >> 2, g = chat & 3;
  int kb = ks * 32 + (lane >> 4) * 8;
  short8 v;
#pragma unroll
  for (int j = 0; j < 8; ++j) {
    int k = kb + j;
    const float* src = W1; int kk = k;
    if (k >= KH) { src = W2; kk = k - KH; }
    float f = 0.f;
    if (u < H && kk < H) f = src[(size_t)(g * H + u) * H + kk];
    v[j] = f2bf(f);
  }
  *(short8*)(dst + (size_t)gid * 8) = v;
}

__global__ void k_pack_wout(const float* __restrict__ Wout, short* __restrict__ dst) {
  int gid = blockIdx.x * 256 + threadIdx.x;          // group of 8
  if (gid >= V * (KH / 8)) return;
  int row = gid / (KH / 8);
  int kb = (gid % (KH / 8)) * 8;
  short8 v;
#pragma unroll
  for (int j = 0; j < 8; ++j) {
    int k = kb + j;
    v[j] = f2bf(k < H ? Wout[(size_t)row * H + k] : 0.f);
  }
  *(short8*)(dst + (size_t)gid * 8) = v;
}

__global__ void k_pack_wih(const float* __restrict__ Wih0, short* __restrict__ dst) {
  int gid = blockIdx.x * 256 + threadIdx.x;          // group of 8
  if (gid >= GP * (KE / 8)) return;
  int chat = gid / (KE / 8);
  int kb = (gid % (KE / 8)) * 8;
  int u = chat >> 2, g = chat & 3;
  short8 v;
#pragma unroll
  for (int j = 0; j < 8; ++j)
    v[j] = f2bf(u < H ? Wih0[(size_t)(g * H + u) * KE + kb + j] : 0.f);
  *(short8*)(dst + (size_t)gid * 8) = v;
}

__global__ void k_pack_bias(const float* ebih0, const float* ebhh0, const float* ebih1, const float* ebhh1,
                            const float* dbih0, const float* dbhh0, const float* dbih1, const float* dbhh1,
                            float* b0e, float* b1e, float* b0d, float* b1d) {
  int chat = blockIdx.x * 256 + threadIdx.x;
  if (chat >= GP) return;
  int u = chat >> 2, g = chat & 3, n = g * H + u;
  bool ok = (u < H);
  b0e[chat] = ok ? ebih0[n] + ebhh0[n] : 0.f;
  b1e[chat] = ok ? ebih1[n] + ebhh1[n] : 0.f;
  b0d[chat] = ok ? dbih0[n] + dbhh0[n] : 0.f;
  b1d[chat] = ok ? dbih1[n] + dbhh1[n] : 0.f;
}

// ---------------- batched input projection ----------------
__global__ void __launch_bounds__(256) k_embproj(const short* __restrict__ WihP,
                                                 const float* __restrict__ emb,
                                                 const int* __restrict__ toks,
                                                 const float* __restrict__ b0P,
                                                 float* __restrict__ X0P) {
  int tid = threadIdx.x, w = tid >> 6, lane = tid & 63, q = lane >> 4, col = lane & 15;
  int mt = blockIdx.x;                 // 0..129
  int ntile = blockIdx.y * 4 + w;      // 0..127
  int tb = ntile * 16 + col;
  int tok = toks[tb];
  const short* Ap = WihP + (size_t)(mt * 16 + col) * KE + q * 8;
  const float* Bp = emb + (size_t)tok * KE + q * 8;
  f32x4 acc = {0.f, 0.f, 0.f, 0.f};
#pragma unroll
  for (int ks = 0; ks < 8; ++ks) {
    short8 a = *(const short8*)(Ap + ks * 32);
    const f32x4* b4 = (const f32x4*)(Bp + ks * 32);
    f32x4 b0v = b4[0], b1v = b4[1];
    short8 bb;
    bb[0]=f2bf(b0v[0]); bb[1]=f2bf(b0v[1]); bb[2]=f2bf(b0v[2]); bb[3]=f2bf(b0v[3]);
    bb[4]=f2bf(b1v[0]); bb[5]=f2bf(b1v[1]); bb[6]=f2bf(b1v[2]); bb[7]=f2bf(b1v[3]);
    acc = __builtin_amdgcn_mfma_f32_16x16x32_bf16(a, bb, acc, 0, 0, 0);
  }
  int chat0 = mt * 16 + q * 4;
  f32x4 bias = *(const f32x4*)(b0P + chat0);
  int t = tb >> 5, b = tb & 31;
  float* dst = X0P + ((size_t)t * GP) * 32 + b;
#pragma unroll
  for (int r = 0; r < 4; ++r)
    dst[(size_t)(chat0 + r) * 32] = acc[r] + bias[r];
}

// ---------------- cooperative recurrence ----------------
// Split-flag pipelined recurrence:
//   phase A: spin flag0>=i -> stage h0 -> acc0 GEMM -> cell0 -> store h0 -> post flag0=i+1
//   phase B: spin flag1>=i -> stage h1 -> acc1 GEMM -> cell1 -> store h1 -> post flag1=i+1
// Each flag is posted ~one phase (~1.2us) before any consumer checks it, so the
// store-visibility + flag-observe MALL round trips are hidden behind the other
// phase's compute in steady state. Hazard argument identical to combined-barrier
// version: flagX[i] implies poster has staged (finished reading) parity (i&1)
// and drained its stores, which is exactly what iteration-i writers need.
struct RecArgs {
  const short *WAe, *WBe, *WAd, *WBd;
  const float *X0e, *X0d, *b1e, *b1d;
  short *hst, *H1P;
  unsigned *bar;            // 65 lines, stride 16 u32 (64B); word0=flag0, word1=flag1
};

__global__ void __launch_bounds__(256) k_recur(RecArgs A) {
  const int tid = threadIdx.x, lane = tid & 63, w = tid >> 6;
  const int q = lane >> 4, col = lane & 15;
  const int mt = w >> 1, nt = w & 1;
  const int bid = blockIdx.x;
  const int chat_l = nt * 16 + col, chat = bid * 32 + chat_l;
  const int am = mt * 16 + col;               // A-fragment row (batch index)
  __shared__ __align__(16) short hs[2][32][HSROW];   // staged h0,h1 (read parity)
  __shared__ float c0[32][8], c1[32][8];
  __shared__ float gbuf[32][33];
  const int tl = tid & 127, cb = tl >> 2, up = tl & 3;
  if (tid < 128) {
    c0[cb][up * 2] = 0.f; c0[cb][up * 2 + 1] = 0.f;
    c1[cb][up * 2] = 0.f; c1[cb][up * 2 + 1] = 0.f;
  }

  // per-layer LDS staging offsets (shorts): chunk c = tid + 256*j, c < 2176
  int loff[9];
#pragma unroll
  for (int j = 0; j < 9; ++j) {
    int c = tid + 256 * j;
    if (c < 2176) { int row = c / 68, kc = c - row * 68; loff[j] = row * HSROW + kc * 8; }
    else loff[j] = 0;
  }
  short* hs0 = &hs[0][0][0];
  short* hs1 = &hs[1][0][0];

  // phase-constant hoists
  const float b1ve = A.b1e[chat], b1vd = A.b1d[chat];
  const short* WAe_p = A.WAe + (size_t)bid * 17408 + (size_t)(nt * 17 * 64 + lane) * 8;
  const short* WAd_p = A.WAd + (size_t)bid * 17408 + (size_t)(nt * 17 * 64 + lane) * 8;
  const short* WBe_p = A.WBe + (size_t)bid * 34816 + (size_t)(nt * 34 * 64 + lane) * 8;
  const short* WBd_p = A.WBd + (size_t)bid * 34816 + (size_t)(nt * 34 * 64 + lane) * 8;

  auto spinwait = [&](int word, unsigned tgt) {
    if (tid < 64) {
      unsigned* p1 = A.bar + lane * 16 + word;
      unsigned* p2 = A.bar + (lane + 1) * 16 + word;
      while (true) {
        unsigned a = __hip_atomic_load(p1, __ATOMIC_RELAXED, __HIP_MEMORY_SCOPE_AGENT);
        unsigned b = __hip_atomic_load(p2, __ATOMIC_RELAXED, __HIP_MEMORY_SCOPE_AGENT);
        if (__all((a >= tgt) && (b >= tgt))) break;
      }
    }
    __syncthreads();
  };

  auto stage = [&](const char* gsrc, short* dst) {
    short8 tmp[9];
#pragma unroll
    for (int j = 0; j < 8; ++j)
      asm volatile("global_load_dwordx4 %0, %1, off sc0 sc1"
                   : "=v"(tmp[j]) : "v"(gsrc + (tid + 256 * j) * 16) : "memory");
    if (tid < 128)   // wave-uniform (waves 0,1): chunks 2048..2175
      asm volatile("global_load_dwordx4 %0, %1, off sc0 sc1"
                   : "=v"(tmp[8]) : "v"(gsrc + (tid + 2048) * 16) : "memory");
    asm volatile("s_waitcnt vmcnt(0)" ::: "memory");
#pragma unroll
    for (int j = 0; j < 8; ++j) *(short8*)(dst + loff[j]) = tmp[j];
    if (tid < 128) *(short8*)(dst + loff[8]) = tmp[8];
    __syncthreads();
  };

  for (int i = 0; i <= 128; ++i) {
    const int rp = (i + 1) & 1, wp = i & 1;

    // ================= phase A: layer 0 (t = i) =================
    if (i > 0) spinwait(0, (unsigned)i);
    // prefetch X0 so it shares the staging latency window (no flag dependency)
    f32x4 xv = {0.f, 0.f, 0.f, 0.f};
    if (i < 128) {
      const float* X0 = (i >> 6) ? A.X0d : A.X0e;
      const int t0 = i & 63;
      xv = *(const f32x4*)(X0 + ((size_t)t0 * GP + chat) * 32 + mt * 16 + q * 4);
    }
    stage((const char*)A.hst + (size_t)rp * 69632, hs0);
    if (i < 128) {
      const short* WA = (i >> 6) ? WAd_p : WAe_p;
      f32x4 acc0 = {0.f, 0.f, 0.f, 0.f};
#pragma unroll
      for (int ks = 0; ks < 17; ++ks) {
        short8 a0 = *(const short8*)&hs[0][am][ks * 32 + q * 8];
        short8 w0 = *(const short8*)(WA + ks * 512);
        acc0 = __builtin_amdgcn_mfma_f32_16x16x32_bf16(a0, w0, acc0, 0, 0, 0);
      }
#pragma unroll
      for (int r = 0; r < 4; ++r)
        gbuf[mt * 16 + q * 4 + r][chat_l] = acc0[r] + xv[r];
      __syncthreads();
      if (tid < 128) {
        unsigned hv = 0;
#pragma unroll
        for (int s = 0; s < 2; ++s) {
          int base = up * 8 + s * 4;
          float gi = gbuf[cb][base + 0], gf = gbuf[cb][base + 1];
          float gg = gbuf[cb][base + 2], go = gbuf[cb][base + 3];
          float c = c0[cb][up * 2 + s];
          float cn = sigm(gf) * c + sigm(gi) * tanh_(gg);
          float hn = sigm(go) * tanh_(cn);
          c0[cb][up * 2 + s] = cn;
          hv |= ((unsigned)(unsigned short)f2bf(hn)) << (16 * s);
        }
        __hip_atomic_store((unsigned*)A.hst + wp * 17408 + cb * 272 + bid * 4 + up, hv,
                           __ATOMIC_RELAXED, __HIP_MEMORY_SCOPE_AGENT);
      }
      asm volatile("s_waitcnt vmcnt(0)" ::: "memory");
      __syncthreads();
      if (tid == 0)
        __hip_atomic_store(A.bar + bid * 16, (unsigned)(i + 1),
                           __ATOMIC_RELAXED, __HIP_MEMORY_SCOPE_AGENT);
    }

    // ================= phase B: layer 1 (t = i-1) =================
    if (i > 0) spinwait(1, (unsigned)i);
    stage((const char*)A.hst + (size_t)rp * 69632 + 34816, hs1);
    if (i >= 1) {
      const int i1 = i - 1, ph1 = i1 >> 6;
      const short* WB = ph1 ? WBd_p : WBe_p;
      const float b1v = ph1 ? b1vd : b1ve;
      f32x4 acc1 = {0.f, 0.f, 0.f, 0.f};
#pragma unroll
      for (int ks = 0; ks < 17; ++ks) {
        short8 a0 = *(const short8*)&hs[0][am][ks * 32 + q * 8];
        short8 a1 = *(const short8*)&hs[1][am][ks * 32 + q * 8];
        short8 w1 = *(const short8*)(WB + ks * 512);
        short8 w2 = *(const short8*)(WB + (size_t)(17 + ks) * 512);
        acc1 = __builtin_amdgcn_mfma_f32_16x16x32_bf16(a0, w1, acc1, 0, 0, 0);
        acc1 = __builtin_amdgcn_mfma_f32_16x16x32_bf16(a1, w2, acc1, 0, 0, 0);
      }
#pragma unroll
      for (int r = 0; r < 4; ++r)
        gbuf[mt * 16 + q * 4 + r][chat_l] = acc1[r] + b1v;
      __syncthreads();
      if (tid < 128) {
        unsigned hv = 0;
#pragma unroll
        for (int s = 0; s < 2; ++s) {
          int base = up * 8 + s * 4;
          float gi = gbuf[cb][base + 0], gf = gbuf[cb][base + 1];
          float gg = gbuf[cb][base + 2], go = gbuf[cb][base + 3];
          float c = c1[cb][up * 2 + s];
          float cn = sigm(gf) * c + sigm(gi) * tanh_(gg);
          float hn = sigm(go) * tanh_(cn);
          c1[cb][up * 2 + s] = cn;
          hv |= ((unsigned)(unsigned short)f2bf(hn)) << (16 * s);
        }
        __hip_atomic_store((unsigned*)A.hst + wp * 17408 + 8704 + cb * 272 + bid * 4 + up, hv,
                           __ATOMIC_RELAXED, __HIP_MEMORY_SCOPE_AGENT);
        if (i1 >= 64)
          *((unsigned*)A.H1P + (size_t)((i1 - 64) * SB + cb) * 272 + bid * 4 + up) = hv;
      }
      if (i < 128) {
        asm volatile("s_waitcnt vmcnt(0)" ::: "memory");
        __syncthreads();
        if (tid == 0)
          __hip_atomic_store(A.bar + bid * 16 + 1, (unsigned)(i + 1),
                             __ATOMIC_RELAXED, __HIP_MEMORY_SCOPE_AGENT);
      }
    } else {
      // i == 0: layer 1 computes nothing; its "output" (zeros) is already
      // globally visible from the host-side memset. Announce readiness.
      if (tid == 0)
        __hip_atomic_store(A.bar + bid * 16 + 1, 1u,
                           __ATOMIC_RELAXED, __HIP_MEMORY_SCOPE_AGENT);
    }
  }
}

// ---------------- projection GEMM + streamed sum-exp ----------------
__global__ void __launch_bounds__(256) k_project(const short* __restrict__ H1P,
                                                 const short* __restrict__ WoutP,
                                                 const float* __restrict__ bout,
                                                 float* __restrict__ partials) {
  int bM = blockIdx.x, bN = blockIdx.y;
  int tid = threadIdx.x, w = tid >> 6, lane = tid & 63, q = lane >> 4, col = lane & 15;
  int wm = w >> 1, wn = w & 1;
  __shared__ __align__(16) short As[128 * 32];
  __shared__ __align__(16) short Bs[128 * 32];
  __shared__ float sred[128][2];
  f32x4 acc[4][4];
#pragma unroll
  for (int mi = 0; mi < 4; ++mi)
#pragma unroll
    for (int ni = 0; ni < 4; ++ni) acc[mi][ni] = (f32x4){0.f, 0.f, 0.f, 0.f};

  for (int ks = 0; ks < 17; ++ks) {
#pragma unroll
    for (int i = 0; i < 2; ++i) {
      int chunk = tid * 2 + i;               // 0..511
      int row = chunk >> 2, ch = chunk & 3;
      ((short8*)As)[chunk] = *(const short8*)(H1P  + (size_t)(bM * 128 + row) * KH + ks * 32 + ch * 8);
      ((short8*)Bs)[chunk] = *(const short8*)(WoutP + (size_t)(bN * 128 + row) * KH + ks * 32 + ch * 8);
    }
    __syncthreads();
    short8 af[4], bf[4];
#pragma unroll
    for (int mi = 0; mi < 4; ++mi) af[mi] = *(const short8*)(As + (wm * 64 + mi * 16 + col) * 32 + q * 8);
#pragma unroll
    for (int ni = 0; ni < 4; ++ni) bf[ni] = *(const short8*)(Bs + (wn * 64 + ni * 16 + col) * 32 + q * 8);
#pragma unroll
    for (int mi = 0; mi < 4; ++mi)
#pragma unroll
      for (int ni = 0; ni < 4; ++ni)
        acc[mi][ni] = __builtin_amdgcn_mfma_f32_16x16x32_bf16(af[mi], bf[ni], acc[mi][ni], 0, 0, 0);
    __syncthreads();
  }
  float bias[4];
#pragma unroll
  for (int ni = 0; ni < 4; ++ni) bias[ni] = bout[bN * 128 + wn * 64 + ni * 16 + col];
#pragma unroll
  for (int mi = 0; mi < 4; ++mi) {
#pragma unroll
    for (int r = 0; r < 4; ++r) {
      float s = 0.f;
#pragma unroll
      for (int ni = 0; ni < 4; ++ni) s += __expf(acc[mi][ni][r] + bias[ni]);
      s += __shfl_xor(s, 1, 64); s += __shfl_xor(s, 2, 64);
      s += __shfl_xor(s, 4, 64); s += __shfl_xor(s, 8, 64);
      if (col == 0) sred[wm * 64 + mi * 16 + q * 4 + r][wn] = s;
    }
  }
  __syncthreads();
  if (tid < 128)
    partials[(size_t)(bM * 128 + tid) * NBN + bN] = sred[tid][0] + sred[tid][1];
}

// ---------------- finish: lse + target logit + loss ----------------
__global__ void __launch_bounds__(256) k_finish(const float* __restrict__ partials,
                                                const short* __restrict__ H1P,
                                                const float* __restrict__ Wout,
                                                const float* __restrict__ bout,
                                                const int* __restrict__ y,
                                                float* __restrict__ out) {
  int tid = threadIdx.x, w = tid >> 6, lane = tid & 63;
  int row = blockIdx.x * 4 + w;           // 0..2047 (t*32+b)
  float s = 0.f;
  for (int j = lane; j < NBN; j += 64) s += partials[(size_t)row * NBN + j];
#pragma unroll
  for (int off = 32; off > 0; off >>= 1) s += __shfl_down(s, off, 64);
  int tok = y[row + 32];                  // y[(t+1)*32 + b]
  float d = 0.f;
  for (int k = lane; k < H; k += 64)
    d += bf2f(H1P[(size_t)row * KH + k]) * Wout[(size_t)tok * H + k];
#pragma unroll
  for (int off = 32; off > 0; off >>= 1) d += __shfl_down(d, off, 64);
  __shared__ float bsum[4];
  if (lane == 0) bsum[w] = __logf(s) - (d + bout[tok]);
  __syncthreads();
  if (tid == 0) atomicAdd(out, (bsum[0] + bsum[1] + bsum[2] + bsum[3]) * (1.f / 32.f));
}

// ---------------- host ----------------
extern "C" void kernel_launch(void* const* d_in, const int* in_sizes, int n_in,
                              void* d_out, int out_size, void* d_ws, size_t ws_size,
                              hipStream_t stream) {
  const int*   x      = (const int*)d_in[0];
  const int*   y      = (const int*)d_in[1];
  const float* encemb = (const float*)d_in[2];
  const float* decemb = (const float*)d_in[3];
  const float* eWih0  = (const float*)d_in[4];
  const float* eWhh0  = (const float*)d_in[5];
  const float* ebih0  = (const float*)d_in[6];
  const float* ebhh0  = (const float*)d_in[7];
  const float* eWih1  = (const float*)d_in[8];
  const float* eWhh1  = (const float*)d_in[9];
  const float* ebih1  = (const float*)d_in[10];
  const float* ebhh1  = (const float*)d_in[11];
  const float* dWih0  = (const float*)d_in[12];
  const float* dWhh0  = (const float*)d_in[13];
  const float* dbih0  = (const float*)d_in[14];
  const float* dbhh0  = (const float*)d_in[15];
  const float* dWih1  = (const float*)d_in[16];
  const float* dWhh1  = (const float*)d_in[17];
  const float* dbih1  = (const float*)d_in[18];
  const float* dbhh1  = (const float*)d_in[19];
  const float* Wout   = (const float*)d_in[20];
  const float* bout   = (const float*)d_in[21];
  float* out = (float*)d_out;

  char* wsb = (char*)d_ws;
  size_t off = 0;
  auto alloc = [&](size_t bytes) -> void* {
    void* p = wsb + off;
    off += (bytes + 255) & ~(size_t)255;
    return p;
  };
  short* WoutP = (short*)alloc((size_t)V * KH * 2);
  short* WAe   = (short*)alloc((size_t)NB * 17408 * 2);
  short* WBe   = (short*)alloc((size_t)NB * 34816 * 2);
  short* WAd   = (short*)alloc((size_t)NB * 17408 * 2);
  short* WBd   = (short*)alloc((size_t)NB * 34816 * 2);
  short* WihPe = (short*)alloc((size_t)GP * KE * 2);
  short* WihPd = (short*)alloc((size_t)GP * KE * 2);
  float* b0e   = (float*)alloc(GP * 4);
  float* b1e   = (float*)alloc(GP * 4);
  float* b0d   = (float*)alloc(GP * 4);
  float* b1d   = (float*)alloc(GP * 4);
  float* X0e   = (float*)alloc((size_t)SEQ * GP * SB * 4);
  float* X0d   = (float*)alloc((size_t)SEQ * GP * SB * 4);
  short* hst   = (short*)alloc((size_t)2 * 2 * 32 * KH * 2);  // [parity][layer][32][544]
  short* H1P   = (short*)alloc((size_t)MROW * KH * 2);
  float* parts = (float*)alloc((size_t)MROW * NBN * 4);
  unsigned* bar = (unsigned*)alloc(NB * 64);

  hipMemsetAsync(d_out, 0, sizeof(float), stream);
  hipMemsetAsync(hst, 0, (size_t)2 * 2 * 32 * KH * 2, stream);
  hipMemsetAsync(bar, 0, NB * 64, stream);

  k_pack_bias<<<(GP + 255) / 256, 256, 0, stream>>>(ebih0, ebhh0, ebih1, ebhh1,
                                                    dbih0, dbhh0, dbih1, dbhh1,
                                                    b0e, b1e, b0d, b1d);
  k_pack_wih<<<(GP * KE / 8 + 255) / 256, 256, 0, stream>>>(eWih0, WihPe);
  k_pack_wih<<<(GP * KE / 8 + 255) / 256, 256, 0, stream>>>(dWih0, WihPd);
  {
    int totA = NB * 2 * 17 * 64, totB = NB * 2 * 34 * 64;
    k_pack_gates<<<(totA + 255) / 256, 256, 0, stream>>>(eWhh0, eWhh0, WAe, 17);
    k_pack_gates<<<(totB + 255) / 256, 256, 0, stream>>>(eWih1, eWhh1, WBe, 34);
    k_pack_gates<<<(totA + 255) / 256, 256, 0, stream>>>(dWhh0, dWhh0, WAd, 17);
    k_pack_gates<<<(totB + 255) / 256, 256, 0, stream>>>(dWih1, dWhh1, WBd, 34);
  }
  k_pack_wout<<<(V * (KH / 8) + 255) / 256, 256, 0, stream>>>(Wout, WoutP);

  k_embproj<<<dim3(GP / 16, 32), 256, 0, stream>>>(WihPe, encemb, x, b0e, X0e);
  k_embproj<<<dim3(GP / 16, 32), 256, 0, stream>>>(WihPd, decemb, y, b0d, X0d);

  RecArgs ra{WAe, WBe, WAd, WBd, X0e, X0d, b1e, b1d, hst, H1P, bar};
  void* kargs[] = {&ra};
  hipLaunchCooperativeKernel((const void*)k_recur, dim3(NB), dim3(256), kargs, 0, stream);

  k_project<<<dim3(MROW / 128, NBN), 256, 0, stream>>>(H1P, WoutP, bout, parts);
  k_finish<<<MROW / 4, 256, 0, stream>>>(parts, H1P, Wout, bout, y, out);
}

// Round 2
// 1370.853 us; speedup vs baseline: 1.0249x; 1.0249x over previous
//
#include <hip/hip_runtime.h>

typedef __attribute__((ext_vector_type(8))) short short8;
typedef __attribute__((ext_vector_type(4))) float f32x4;
typedef unsigned long long ull;

constexpr int H    = 516;    // hidden
constexpr int GP   = 2080;   // padded gate cols (65*32), permuted chat = 4*u+g
constexpr int KH   = 544;    // padded hidden K (17*32)
constexpr int KE   = 256;    // embedding dim
constexpr int NB   = 65;     // recurrence blocks (8 units each -> 520 padded units)
constexpr int SB   = 32;     // batch
constexpr int SEQ  = 64;
constexpr int MROW = 2048;   // SEQ*SB
constexpr int V    = 32000;
constexpr int NBN  = 250;    // V/128

__device__ __forceinline__ float bf2f(short s) {
  unsigned u = ((unsigned)(unsigned short)s) << 16;
  float f; __builtin_memcpy(&f, &u, 4); return f;
}
__device__ __forceinline__ short f2bf(float f) {
  unsigned u; __builtin_memcpy(&u, &f, 4);
  u += 0x7fffu + ((u >> 16) & 1u);
  return (short)(u >> 16);
}
__device__ __forceinline__ float sigm(float x){ return 1.f/(1.f+__expf(-x)); }
__device__ __forceinline__ float tanh_(float x){ float e=__expf(-2.f*x); return (1.f-e)/(1.f+e); }

// ---------------- pack kernels ----------------
__global__ void k_pack_gates(const float* __restrict__ W1, const float* __restrict__ W2,
                             short* __restrict__ dst, int ksteps) {
  int gid = blockIdx.x * 256 + threadIdx.x;
  int total = NB * 2 * ksteps * 64;
  if (gid >= total) return;
  int lane = gid & 63;
  int rest = gid >> 6;
  int ks = rest % ksteps; rest /= ksteps;
  int nt = rest & 1; int bid = rest >> 1;
  int chat = bid * 32 + nt * 16 + (lane & 15);
  int u = chat >> 2, g = chat & 3;
  int kb = ks * 32 + (lane >> 4) * 8;
  short8 v;
#pragma unroll
  for (int j = 0; j < 8; ++j) {
    int k = kb + j;
    const float* src = W1; int kk = k;
    if (k >= KH) { src = W2; kk = k - KH; }
    float f = 0.f;
    if (u < H && kk < H) f = src[(size_t)(g * H + u) * H + kk];
    v[j] = f2bf(f);
  }
  *(short8*)(dst + (size_t)gid * 8) = v;
}

__global__ void k_pack_wout(const float* __restrict__ Wout, short* __restrict__ dst) {
  int gid = blockIdx.x * 256 + threadIdx.x;          // group of 8
  if (gid >= V * (KH / 8)) return;
  int row = gid / (KH / 8);
  int kb = (gid % (KH / 8)) * 8;
  short8 v;
#pragma unroll
  for (int j = 0; j < 8; ++j) {
    int k = kb + j;
    v[j] = f2bf(k < H ? Wout[(size_t)row * H + k] : 0.f);
  }
  *(short8*)(dst + (size_t)gid * 8) = v;
}

__global__ void k_pack_wih(const float* __restrict__ Wih0, short* __restrict__ dst) {
  int gid = blockIdx.x * 256 + threadIdx.x;          // group of 8
  if (gid >= GP * (KE / 8)) return;
  int chat = gid / (KE / 8);
  int kb = (gid % (KE / 8)) * 8;
  int u = chat >> 2, g = chat & 3;
  short8 v;
#pragma unroll
  for (int j = 0; j < 8; ++j)
    v[j] = f2bf(u < H ? Wih0[(size_t)(g * H + u) * KE + kb + j] : 0.f);
  *(short8*)(dst + (size_t)gid * 8) = v;
}

__global__ void k_pack_bias(const float* ebih0, const float* ebhh0, const float* ebih1, const float* ebhh1,
                            const float* dbih0, const float* dbhh0, const float* dbih1, const float* dbhh1,
                            float* b0e, float* b1e, float* b0d, float* b1d) {
  int chat = blockIdx.x * 256 + threadIdx.x;
  if (chat >= GP) return;
  int u = chat >> 2, g = chat & 3, n = g * H + u;
  bool ok = (u < H);
  b0e[chat] = ok ? ebih0[n] + ebhh0[n] : 0.f;
  b1e[chat] = ok ? ebih1[n] + ebhh1[n] : 0.f;
  b0d[chat] = ok ? dbih0[n] + dbhh0[n] : 0.f;
  b1d[chat] = ok ? dbih1[n] + dbhh1[n] : 0.f;
}

// ---------------- batched input projection ----------------
__global__ void __launch_bounds__(256) k_embproj(const short* __restrict__ WihP,
                                                 const float* __restrict__ emb,
                                                 const int* __restrict__ toks,
                                                 const float* __restrict__ b0P,
                                                 float* __restrict__ X0P) {
  int tid = threadIdx.x, w = tid >> 6, lane = tid & 63, q = lane >> 4, col = lane & 15;
  int mt = blockIdx.x;                 // 0..129
  int ntile = blockIdx.y * 4 + w;      // 0..127
  int tb = ntile * 16 + col;
  int tok = toks[tb];
  const short* Ap = WihP + (size_t)(mt * 16 + col) * KE + q * 8;
  const float* Bp = emb + (size_t)tok * KE + q * 8;
  f32x4 acc = {0.f, 0.f, 0.f, 0.f};
#pragma unroll
  for (int ks = 0; ks < 8; ++ks) {
    short8 a = *(const short8*)(Ap + ks * 32);
    const f32x4* b4 = (const f32x4*)(Bp + ks * 32);
    f32x4 b0v = b4[0], b1v = b4[1];
    short8 bb;
    bb[0]=f2bf(b0v[0]); bb[1]=f2bf(b0v[1]); bb[2]=f2bf(b0v[2]); bb[3]=f2bf(b0v[3]);
    bb[4]=f2bf(b1v[0]); bb[5]=f2bf(b1v[1]); bb[6]=f2bf(b1v[2]); bb[7]=f2bf(b1v[3]);
    acc = __builtin_amdgcn_mfma_f32_16x16x32_bf16(a, bb, acc, 0, 0, 0);
  }
  int chat0 = mt * 16 + q * 4;
  f32x4 bias = *(const f32x4*)(b0P + chat0);
  int t = tb >> 5, b = tb & 31;
  float* dst = X0P + ((size_t)t * GP) * 32 + b;
#pragma unroll
  for (int r = 0; r < 4; ++r)
    dst[(size_t)(chat0 + r) * 32] = acc[r] + bias[r];
}

// ---------------- cooperative recurrence ----------------
// Round-0 sync structure (single flag/block/iter, proven), dataflow rebuilt:
//  - weights register-resident per phase (w0[17],w1[17],w2[17] = 204 VGPR),
//    reloaded from L2 once at i==64 / i==65. Removes per-iter 104KB L2 stream.
//  - A-fragments loaded per-lane directly from hst via sc0/sc1 bypass loads
//    (17+17 x 16B, imm-offset folded). Removes LDS h-staging entirely
//    (burst-wait + ds_write + syncthreads + 136 ds_read_b128/iter + conflicts).
//  - Hazards unchanged vs round-0: in-order vmcnt drains fragment reads
//    before the h-store drain that gates the flag post; consumers load only
//    after observing all flags >= i (RAW), writers store parity p only after
//    all blocks flagged completion of the iteration that read p (WAR).
struct RecArgs {
  const short *WAe, *WBe, *WAd, *WBd;
  const float *X0e, *X0d, *b1e, *b1d;
  short *hst, *H1P;
  unsigned *bar;            // 65 flags, stride 16 u32 (64B)
};

__global__ void __launch_bounds__(256, 1) k_recur(RecArgs A) {
  const int tid = threadIdx.x, lane = tid & 63, w = tid >> 6;
  const int q = lane >> 4, col = lane & 15;
  const int mt = w >> 1, nt = w & 1;
  const int bid = blockIdx.x;
  const int chat_l = nt * 16 + col, chat = bid * 32 + chat_l;
  const int am = mt * 16 + col;               // A-fragment row (batch index)
  __shared__ float c0[32][8], c1[32][8];
  __shared__ float gbuf0[32][33], gbuf1[32][33];
  const int tl = tid & 127, cb = tl >> 2, up = tl & 3;
  if (tid < 128) { c0[cb][up * 2] = 0.f; c0[cb][up * 2 + 1] = 0.f; }
  else           { c1[cb][up * 2] = 0.f; c1[cb][up * 2 + 1] = 0.f; }

  // phase-constant hoists
  const float b1ve = A.b1e[chat], b1vd = A.b1d[chat];
  const short* WAe_p = A.WAe + (size_t)bid * 17408 + (size_t)(nt * 17 * 64 + lane) * 8;
  const short* WAd_p = A.WAd + (size_t)bid * 17408 + (size_t)(nt * 17 * 64 + lane) * 8;
  const short* WBe_p = A.WBe + (size_t)bid * 34816 + (size_t)(nt * 34 * 64 + lane) * 8;
  const short* WBd_p = A.WBd + (size_t)bid * 34816 + (size_t)(nt * 34 * 64 + lane) * 8;

  // per-lane fragment base (bytes): hst[parity][layer][am][k], row stride 1088B
  const char* hb = (const char*)A.hst + (size_t)am * 1088 + q * 16;

  short8 w0[17], w1[17], w2[17];

  for (int i = 0; i <= 128; ++i) {
    const int rp = (i + 1) & 1, wp = i & 1;

    // ---- phase-boundary weight (re)loads into registers ----
    if (i == 0) {
#pragma unroll
      for (int ks = 0; ks < 17; ++ks) w0[ks] = *(const short8*)(WAe_p + ks * 512);
#pragma unroll
      for (int ks = 0; ks < 17; ++ks) {
        w1[ks] = *(const short8*)(WBe_p + ks * 512);
        w2[ks] = *(const short8*)(WBe_p + (size_t)(17 + ks) * 512);
      }
    } else if (i == 64) {
#pragma unroll
      for (int ks = 0; ks < 17; ++ks) w0[ks] = *(const short8*)(WAd_p + ks * 512);
    } else if (i == 65) {
#pragma unroll
      for (int ks = 0; ks < 17; ++ks) {
        w1[ks] = *(const short8*)(WBd_p + ks * 512);
        w2[ks] = *(const short8*)(WBd_p + (size_t)(17 + ks) * 512);
      }
    }

    // ---- X0 prefetch (no flag dependency) ----
    f32x4 xv = {0.f, 0.f, 0.f, 0.f};
    if (i < 128) {
      const float* X0 = (i >> 6) ? A.X0d : A.X0e;
      const int t0 = i & 63;
      xv = *(const f32x4*)(X0 + ((size_t)t0 * GP + chat) * 32 + mt * 16 + q * 4);
    }

    // ---- direct per-lane fragment loads (bypass, MALL-coherent) ----
    const char* h0b = hb + (size_t)rp * 69632;
    const char* h1b = h0b + 34816;
    short8 a0[17], a1[17];
#pragma unroll
    for (int ks = 0; ks < 17; ++ks)
      asm volatile("global_load_dwordx4 %0, %1, off sc0 sc1"
                   : "=v"(a0[ks]) : "v"(h0b + ks * 64) : "memory");
#pragma unroll
    for (int ks = 0; ks < 17; ++ks)
      asm volatile("global_load_dwordx4 %0, %1, off sc0 sc1"
                   : "=v"(a1[ks]) : "v"(h1b + ks * 64) : "memory");
    asm volatile("s_waitcnt vmcnt(0)" ::: "memory");
    __builtin_amdgcn_sched_barrier(0);

    // ---- both layers' gate GEMMs from registers ----
    f32x4 acc0 = {0.f, 0.f, 0.f, 0.f}, acc1 = {0.f, 0.f, 0.f, 0.f};
    if (i < 128) {
#pragma unroll
      for (int ks = 0; ks < 17; ++ks)
        acc0 = __builtin_amdgcn_mfma_f32_16x16x32_bf16(a0[ks], w0[ks], acc0, 0, 0, 0);
    }
    if (i >= 1) {
#pragma unroll
      for (int ks = 0; ks < 17; ++ks) {
        acc1 = __builtin_amdgcn_mfma_f32_16x16x32_bf16(a0[ks], w1[ks], acc1, 0, 0, 0);
        acc1 = __builtin_amdgcn_mfma_f32_16x16x32_bf16(a1[ks], w2[ks], acc1, 0, 0, 0);
      }
    }
    {
      const float b1v = ((i >= 1) ? ((i - 1) >> 6) : 0) ? b1vd : b1ve;
#pragma unroll
      for (int r = 0; r < 4; ++r) {
        gbuf0[mt * 16 + q * 4 + r][chat_l] = acc0[r] + xv[r];
        gbuf1[mt * 16 + q * 4 + r][chat_l] = acc1[r] + b1v;
      }
    }
    __syncthreads();

    // ---- cell updates: L0 on tid<128 (t=i), L1 on tid>=128 (t=i-1) ----
    if (tid < 128) {
      if (i < 128) {
        unsigned hv = 0;
#pragma unroll
        for (int s = 0; s < 2; ++s) {
          int base = up * 8 + s * 4;
          float gi = gbuf0[cb][base + 0], gf = gbuf0[cb][base + 1];
          float gg = gbuf0[cb][base + 2], go = gbuf0[cb][base + 3];
          float c = c0[cb][up * 2 + s];
          float cn = sigm(gf) * c + sigm(gi) * tanh_(gg);
          float hn = sigm(go) * tanh_(cn);
          c0[cb][up * 2 + s] = cn;
          hv |= ((unsigned)(unsigned short)f2bf(hn)) << (16 * s);
        }
        __hip_atomic_store((unsigned*)A.hst + wp * 17408 + cb * 272 + bid * 4 + up, hv,
                           __ATOMIC_RELAXED, __HIP_MEMORY_SCOPE_AGENT);
      }
    } else {
      if (i >= 1) {
        const int i1 = i - 1;
        unsigned hv = 0;
#pragma unroll
        for (int s = 0; s < 2; ++s) {
          int base = up * 8 + s * 4;
          float gi = gbuf1[cb][base + 0], gf = gbuf1[cb][base + 1];
          float gg = gbuf1[cb][base + 2], go = gbuf1[cb][base + 3];
          float c = c1[cb][up * 2 + s];
          float cn = sigm(gf) * c + sigm(gi) * tanh_(gg);
          float hn = sigm(go) * tanh_(cn);
          c1[cb][up * 2 + s] = cn;
          hv |= ((unsigned)(unsigned short)f2bf(hn)) << (16 * s);
        }
        __hip_atomic_store((unsigned*)A.hst + wp * 17408 + 8704 + cb * 272 + bid * 4 + up, hv,
                           __ATOMIC_RELAXED, __HIP_MEMORY_SCOPE_AGENT);
        if (i1 >= 64)
          *((unsigned*)A.H1P + (size_t)((i1 - 64) * SB + cb) * 272 + bid * 4 + up) = hv;
      }
    }

    // ---- flag-array barrier ----
    if (i < 128) {
      asm volatile("s_waitcnt vmcnt(0)" ::: "memory");
      __syncthreads();
      if (tid == 0)
        __hip_atomic_store(A.bar + bid * 16, (unsigned)(i + 1),
                           __ATOMIC_RELAXED, __HIP_MEMORY_SCOPE_AGENT);
      if (tid < 64) {
        const unsigned tgt = (unsigned)(i + 1);
        unsigned* p1 = A.bar + lane * 16;
        unsigned* p2 = A.bar + (lane + 1) * 16;
        while (true) {
          unsigned a = __hip_atomic_load(p1, __ATOMIC_RELAXED, __HIP_MEMORY_SCOPE_AGENT);
          unsigned b = __hip_atomic_load(p2, __ATOMIC_RELAXED, __HIP_MEMORY_SCOPE_AGENT);
          if (__all((a >= tgt) && (b >= tgt))) break;
        }
      }
      __syncthreads();
    }
  }
}

// ---------------- projection GEMM + streamed sum-exp ----------------
__global__ void __launch_bounds__(256) k_project(const short* __restrict__ H1P,
                                                 const short* __restrict__ WoutP,
                                                 const float* __restrict__ bout,
                                                 float* __restrict__ partials) {
  int bM = blockIdx.x, bN = blockIdx.y;
  int tid = threadIdx.x, w = tid >> 6, lane = tid & 63, q = lane >> 4, col = lane & 15;
  int wm = w >> 1, wn = w & 1;
  __shared__ __align__(16) short As[128 * 32];
  __shared__ __align__(16) short Bs[128 * 32];
  __shared__ float sred[128][2];
  f32x4 acc[4][4];
#pragma unroll
  for (int mi = 0; mi < 4; ++mi)
#pragma unroll
    for (int ni = 0; ni < 4; ++ni) acc[mi][ni] = (f32x4){0.f, 0.f, 0.f, 0.f};

  for (int ks = 0; ks < 17; ++ks) {
#pragma unroll
    for (int i = 0; i < 2; ++i) {
      int chunk = tid * 2 + i;               // 0..511
      int row = chunk >> 2, ch = chunk & 3;
      ((short8*)As)[chunk] = *(const short8*)(H1P  + (size_t)(bM * 128 + row) * KH + ks * 32 + ch * 8);
      ((short8*)Bs)[chunk] = *(const short8*)(WoutP + (size_t)(bN * 128 + row) * KH + ks * 32 + ch * 8);
    }
    __syncthreads();
    short8 af[4], bf[4];
#pragma unroll
    for (int mi = 0; mi < 4; ++mi) af[mi] = *(const short8*)(As + (wm * 64 + mi * 16 + col) * 32 + q * 8);
#pragma unroll
    for (int ni = 0; ni < 4; ++ni) bf[ni] = *(const short8*)(Bs + (wn * 64 + ni * 16 + col) * 32 + q * 8);
#pragma unroll
    for (int mi = 0; mi < 4; ++mi)
#pragma unroll
      for (int ni = 0; ni < 4; ++ni)
        acc[mi][ni] = __builtin_amdgcn_mfma_f32_16x16x32_bf16(af[mi], bf[ni], acc[mi][ni], 0, 0, 0);
    __syncthreads();
  }
  float bias[4];
#pragma unroll
  for (int ni = 0; ni < 4; ++ni) bias[ni] = bout[bN * 128 + wn * 64 + ni * 16 + col];
#pragma unroll
  for (int mi = 0; mi < 4; ++mi) {
#pragma unroll
    for (int r = 0; r < 4; ++r) {
      float s = 0.f;
#pragma unroll
      for (int ni = 0; ni < 4; ++ni) s += __expf(acc[mi][ni][r] + bias[ni]);
      s += __shfl_xor(s, 1, 64); s += __shfl_xor(s, 2, 64);
      s += __shfl_xor(s, 4, 64); s += __shfl_xor(s, 8, 64);
      if (col == 0) sred[wm * 64 + mi * 16 + q * 4 + r][wn] = s;
    }
  }
  __syncthreads();
  if (tid < 128)
    partials[(size_t)(bM * 128 + tid) * NBN + bN] = sred[tid][0] + sred[tid][1];
}

// ---------------- finish: lse + target logit + loss ----------------
__global__ void __launch_bounds__(256) k_finish(const float* __restrict__ partials,
                                                const short* __restrict__ H1P,
                                                const float* __restrict__ Wout,
                                                const float* __restrict__ bout,
                                                const int* __restrict__ y,
                                                float* __restrict__ out) {
  int tid = threadIdx.x, w = tid >> 6, lane = tid & 63;
  int row = blockIdx.x * 4 + w;           // 0..2047 (t*32+b)
  float s = 0.f;
  for (int j = lane; j < NBN; j += 64) s += partials[(size_t)row * NBN + j];
#pragma unroll
  for (int off = 32; off > 0; off >>= 1) s += __shfl_down(s, off, 64);
  int tok = y[row + 32];                  // y[(t+1)*32 + b]
  float d = 0.f;
  for (int k = lane; k < H; k += 64)
    d += bf2f(H1P[(size_t)row * KH + k]) * Wout[(size_t)tok * H + k];
#pragma unroll
  for (int off = 32; off > 0; off >>= 1) d += __shfl_down(d, off, 64);
  __shared__ float bsum[4];
  if (lane == 0) bsum[w] = __logf(s) - (d + bout[tok]);
  __syncthreads();
  if (tid == 0) atomicAdd(out, (bsum[0] + bsum[1] + bsum[2] + bsum[3]) * (1.f / 32.f));
}

// ---------------- host ----------------
extern "C" void kernel_launch(void* const* d_in, const int* in_sizes, int n_in,
                              void* d_out, int out_size, void* d_ws, size_t ws_size,
                              hipStream_t stream) {
  const int*   x      = (const int*)d_in[0];
  const int*   y      = (const int*)d_in[1];
  const float* encemb = (const float*)d_in[2];
  const float* decemb = (const float*)d_in[3];
  const float* eWih0  = (const float*)d_in[4];
  const float* eWhh0  = (const float*)d_in[5];
  const float* ebih0  = (const float*)d_in[6];
  const float* ebhh0  = (const float*)d_in[7];
  const float* eWih1  = (const float*)d_in[8];
  const float* eWhh1  = (const float*)d_in[9];
  const float* ebih1  = (const float*)d_in[10];
  const float* ebhh1  = (const float*)d_in[11];
  const float* dWih0  = (const float*)d_in[12];
  const float* dWhh0  = (const float*)d_in[13];
  const float* dbih0  = (const float*)d_in[14];
  const float* dbhh0  = (const float*)d_in[15];
  const float* dWih1  = (const float*)d_in[16];
  const float* dWhh1  = (const float*)d_in[17];
  const float* dbih1  = (const float*)d_in[18];
  const float* dbhh1  = (const float*)d_in[19];
  const float* Wout   = (const float*)d_in[20];
  const float* bout   = (const float*)d_in[21];
  float* out = (float*)d_out;

  char* wsb = (char*)d_ws;
  size_t off = 0;
  auto alloc = [&](size_t bytes) -> void* {
    void* p = wsb + off;
    off += (bytes + 255) & ~(size_t)255;
    return p;
  };
  short* WoutP = (short*)alloc((size_t)V * KH * 2);
  short* WAe   = (short*)alloc((size_t)NB * 17408 * 2);
  short* WBe   = (short*)alloc((size_t)NB * 34816 * 2);
  short* WAd   = (short*)alloc((size_t)NB * 17408 * 2);
  short* WBd   = (short*)alloc((size_t)NB * 34816 * 2);
  short* WihPe = (short*)alloc((size_t)GP * KE * 2);
  short* WihPd = (short*)alloc((size_t)GP * KE * 2);
  float* b0e   = (float*)alloc(GP * 4);
  float* b1e   = (float*)alloc(GP * 4);
  float* b0d   = (float*)alloc(GP * 4);
  float* b1d   = (float*)alloc(GP * 4);
  float* X0e   = (float*)alloc((size_t)SEQ * GP * SB * 4);
  float* X0d   = (float*)alloc((size_t)SEQ * GP * SB * 4);
  short* hst   = (short*)alloc((size_t)2 * 2 * 32 * KH * 2);  // [parity][layer][32][544]
  short* H1P   = (short*)alloc((size_t)MROW * KH * 2);
  float* parts = (float*)alloc((size_t)MROW * NBN * 4);
  unsigned* bar = (unsigned*)alloc(NB * 64);

  hipMemsetAsync(d_out, 0, sizeof(float), stream);
  hipMemsetAsync(hst, 0, (size_t)2 * 2 * 32 * KH * 2, stream);
  hipMemsetAsync(bar, 0, NB * 64, stream);

  k_pack_bias<<<(GP + 255) / 256, 256, 0, stream>>>(ebih0, ebhh0, ebih1, ebhh1,
                                                    dbih0, dbhh0, dbih1, dbhh1,
                                                    b0e, b1e, b0d, b1d);
  k_pack_wih<<<(GP * KE / 8 + 255) / 256, 256, 0, stream>>>(eWih0, WihPe);
  k_pack_wih<<<(GP * KE / 8 + 255) / 256, 256, 0, stream>>>(dWih0, WihPd);
  {
    int totA = NB * 2 * 17 * 64, totB = NB * 2 * 34 * 64;
    k_pack_gates<<<(totA + 255) / 256, 256, 0, stream>>>(eWhh0, eWhh0, WAe, 17);
    k_pack_gates<<<(totB + 255) / 256, 256, 0, stream>>>(eWih1, eWhh1, WBe, 34);
    k_pack_gates<<<(totA + 255) / 256, 256, 0, stream>>>(dWhh0, dWhh0, WAd, 17);
    k_pack_gates<<<(totB + 255) / 256, 256, 0, stream>>>(dWih1, dWhh1, WBd, 34);
  }
  k_pack_wout<<<(V * (KH / 8) + 255) / 256, 256, 0, stream>>>(Wout, WoutP);

  k_embproj<<<dim3(GP / 16, 32), 256, 0, stream>>>(WihPe, encemb, x, b0e, X0e);
  k_embproj<<<dim3(GP / 16, 32), 256, 0, stream>>>(WihPd, decemb, y, b0d, X0d);

  RecArgs ra{WAe, WBe, WAd, WBd, X0e, X0d, b1e, b1d, hst, H1P, bar};
  void* kargs[] = {&ra};
  hipLaunchCooperativeKernel((const void*)k_recur, dim3(NB), dim3(256), kargs, 0, stream);

  k_project<<<dim3(MROW / 128, NBN), 256, 0, stream>>>(H1P, WoutP, bout, parts);
  k_finish<<<MROW / 4, 256, 0, stream>>>(parts, H1P, Wout, bout, y, out);
}

// Round 3
// 1085.513 us; speedup vs baseline: 1.2943x; 1.2629x over previous
//
#include <hip/hip_runtime.h>

typedef __attribute__((ext_vector_type(8))) short short8;
typedef __attribute__((ext_vector_type(4))) float f32x4;
typedef unsigned long long ull;

constexpr int H    = 516;    // hidden
constexpr int GP   = 2080;   // padded gate cols (65*32), permuted chat = 4*u+g
constexpr int KH   = 544;    // padded hidden K (17*32)
constexpr int KE   = 256;    // embedding dim
constexpr int NB   = 65;     // recurrence blocks (8 units each -> 520 padded units)
constexpr int SB   = 32;     // batch
constexpr int SEQ  = 64;
constexpr int MROW = 2048;   // SEQ*SB
constexpr int V    = 32000;
constexpr int NBN  = 250;    // V/128
constexpr int HR   = 552;    // padded h row (shorts); global hst uses same stride
// hst layout: [parity][layer][32][HR] bf16 -> parity stride 70656B, layer 35328B

__device__ __forceinline__ float bf2f(short s) {
  unsigned u = ((unsigned)(unsigned short)s) << 16;
  float f; __builtin_memcpy(&f, &u, 4); return f;
}
__device__ __forceinline__ short f2bf(float f) {
  unsigned u; __builtin_memcpy(&u, &f, 4);
  u += 0x7fffu + ((u >> 16) & 1u);
  return (short)(u >> 16);
}
__device__ __forceinline__ float sigm(float x){ return 1.f/(1.f+__expf(-x)); }
__device__ __forceinline__ float tanh_(float x){ float e=__expf(-2.f*x); return (1.f-e)/(1.f+e); }

// ---------------- pack kernels ----------------
__global__ void k_pack_gates(const float* __restrict__ W1, const float* __restrict__ W2,
                             short* __restrict__ dst, int ksteps) {
  int gid = blockIdx.x * 256 + threadIdx.x;
  int total = NB * 2 * ksteps * 64;
  if (gid >= total) return;
  int lane = gid & 63;
  int rest = gid >> 6;
  int ks = rest % ksteps; rest /= ksteps;
  int nt = rest & 1; int bid = rest >> 1;
  int chat = bid * 32 + nt * 16 + (lane & 15);
  int u = chat >> 2, g = chat & 3;
  int kb = ks * 32 + (lane >> 4) * 8;
  short8 v;
#pragma unroll
  for (int j = 0; j < 8; ++j) {
    int k = kb + j;
    const float* src = W1; int kk = k;
    if (k >= KH) { src = W2; kk = k - KH; }
    float f = 0.f;
    if (u < H && kk < H) f = src[(size_t)(g * H + u) * H + kk];
    v[j] = f2bf(f);
  }
  *(short8*)(dst + (size_t)gid * 8) = v;
}

__global__ void k_pack_wout(const float* __restrict__ Wout, short* __restrict__ dst) {
  int gid = blockIdx.x * 256 + threadIdx.x;          // group of 8
  if (gid >= V * (KH / 8)) return;
  int row = gid / (KH / 8);
  int kb = (gid % (KH / 8)) * 8;
  short8 v;
#pragma unroll
  for (int j = 0; j < 8; ++j) {
    int k = kb + j;
    v[j] = f2bf(k < H ? Wout[(size_t)row * H + k] : 0.f);
  }
  *(short8*)(dst + (size_t)gid * 8) = v;
}

__global__ void k_pack_wih(const float* __restrict__ Wih0, short* __restrict__ dst) {
  int gid = blockIdx.x * 256 + threadIdx.x;          // group of 8
  if (gid >= GP * (KE / 8)) return;
  int chat = gid / (KE / 8);
  int kb = (gid % (KE / 8)) * 8;
  int u = chat >> 2, g = chat & 3;
  short8 v;
#pragma unroll
  for (int j = 0; j < 8; ++j)
    v[j] = f2bf(u < H ? Wih0[(size_t)(g * H + u) * KE + kb + j] : 0.f);
  *(short8*)(dst + (size_t)gid * 8) = v;
}

__global__ void k_pack_bias(const float* ebih0, const float* ebhh0, const float* ebih1, const float* ebhh1,
                            const float* dbih0, const float* dbhh0, const float* dbih1, const float* dbhh1,
                            float* b0e, float* b1e, float* b0d, float* b1d) {
  int chat = blockIdx.x * 256 + threadIdx.x;
  if (chat >= GP) return;
  int u = chat >> 2, g = chat & 3, n = g * H + u;
  bool ok = (u < H);
  b0e[chat] = ok ? ebih0[n] + ebhh0[n] : 0.f;
  b1e[chat] = ok ? ebih1[n] + ebhh1[n] : 0.f;
  b0d[chat] = ok ? dbih0[n] + dbhh0[n] : 0.f;
  b1d[chat] = ok ? dbih1[n] + dbhh1[n] : 0.f;
}

// ---------------- batched input projection ----------------
__global__ void __launch_bounds__(256) k_embproj(const short* __restrict__ WihP,
                                                 const float* __restrict__ emb,
                                                 const int* __restrict__ toks,
                                                 const float* __restrict__ b0P,
                                                 float* __restrict__ X0P) {
  int tid = threadIdx.x, w = tid >> 6, lane = tid & 63, q = lane >> 4, col = lane & 15;
  int mt = blockIdx.x;                 // 0..129
  int ntile = blockIdx.y * 4 + w;      // 0..127
  int tb = ntile * 16 + col;
  int tok = toks[tb];
  const short* Ap = WihP + (size_t)(mt * 16 + col) * KE + q * 8;
  const float* Bp = emb + (size_t)tok * KE + q * 8;
  f32x4 acc = {0.f, 0.f, 0.f, 0.f};
#pragma unroll
  for (int ks = 0; ks < 8; ++ks) {
    short8 a = *(const short8*)(Ap + ks * 32);
    const f32x4* b4 = (const f32x4*)(Bp + ks * 32);
    f32x4 b0v = b4[0], b1v = b4[1];
    short8 bb;
    bb[0]=f2bf(b0v[0]); bb[1]=f2bf(b0v[1]); bb[2]=f2bf(b0v[2]); bb[3]=f2bf(b0v[3]);
    bb[4]=f2bf(b1v[0]); bb[5]=f2bf(b1v[1]); bb[6]=f2bf(b1v[2]); bb[7]=f2bf(b1v[3]);
    acc = __builtin_amdgcn_mfma_f32_16x16x32_bf16(a, bb, acc, 0, 0, 0);
  }
  int chat0 = mt * 16 + q * 4;
  f32x4 bias = *(const f32x4*)(b0P + chat0);
  int t = tb >> 5, b = tb & 31;
  float* dst = X0P + ((size_t)t * GP) * 32 + b;
#pragma unroll
  for (int r = 0; r < 4; ++r)
    dst[(size_t)(chat0 + r) * 32] = acc[r] + bias[r];
}

// ---------------- cooperative recurrence ----------------
// Round-0 sync skeleton (single flag/block/iter, coalesced LDS stage) with the
// per-iter 209KB/block weight L2 stream removed: ONE GEMM PRODUCT PER WAVE.
//   wave0: acc0 = A0*W0 (all 4 16x16 tiles)  -> gbuf0 (+X0)
//   wave1: A0*W1 partial of acc1             -> gbuf1a (+b1)
//   wave2: A1*W2 partial of acc1             -> gbuf1b
//   wave3: GEMM-idle; stages the tail chunk
// Each wave keeps its product's 34 weight fragments register-resident
// (136 VGPR), reloaded at enc->dec switch (i==64 for W0, i==65 for W1/W2).
// Peak VGPR ~235 (stage tmp and accs don't overlap weights+tmp window).
// hst is 552-padded so stage is fully linear (no div table, clean ds_writes).
struct RecArgs {
  const short *WAe, *WBe, *WAd, *WBd;
  const float *X0e, *X0d, *b1e, *b1d;
  short *hst, *H1P;
  unsigned *bar;            // 65 flags, stride 16 u32 (64B)
};

__global__ void __launch_bounds__(256, 1) k_recur(RecArgs A) {
  const int tid = threadIdx.x, lane = tid & 63, w = tid >> 6;
  const int q = lane >> 4, col = lane & 15;
  const int bid = blockIdx.x;
  __shared__ __align__(16) short hs[2][32][HR];      // staged h0,h1 (read parity)
  __shared__ float c0[32][8], c1[32][8];
  __shared__ float gbuf0[32][33], gbuf1a[32][33], gbuf1b[32][33];
  const int tl = tid & 127, cb = tl >> 2, up = tl & 3;
  if (tid < 128) { c0[cb][up * 2] = 0.f; c0[cb][up * 2 + 1] = 0.f; }
  else           { c1[cb][up * 2] = 0.f; c1[cb][up * 2 + 1] = 0.f; }

  // wave-specific weight sources (one product per wave)
  const short *wptr_e, *wptr_d; int nstr, reload_i;
  if (w == 0) {
    wptr_e = A.WAe + (size_t)bid * 17408 + lane * 8;
    wptr_d = A.WAd + (size_t)bid * 17408 + lane * 8;
    nstr = 8704; reload_i = 64;
  } else if (w == 1) {
    wptr_e = A.WBe + (size_t)bid * 34816 + lane * 8;
    wptr_d = A.WBd + (size_t)bid * 34816 + lane * 8;
    nstr = 17408; reload_i = 65;
  } else {
    wptr_e = A.WBe + (size_t)bid * 34816 + 8704 + lane * 8;
    wptr_d = A.WBd + (size_t)bid * 34816 + 8704 + lane * 8;
    nstr = 17408; reload_i = 65;
  }

  short8 wreg[34];
  float b1v0 = 0.f, b1v1 = 0.f;

  const short* arow = (w == 2) ? &hs[1][0][0] : &hs[0][0][0];
  const int aoff0 = col * HR + q * 8, aoff1 = (col + 16) * HR + q * 8;

  for (int i = 0; i <= 128; ++i) {
    const int rp = (i + 1) & 1, wp = i & 1;

    // ---- phase-boundary weight reloads into registers ----
    if (i == 0 || i == reload_i) {
      const short* wb = (i == 0) ? wptr_e : wptr_d;
      if (w < 3) {
#pragma unroll
        for (int ks = 0; ks < 17; ++ks) {
          wreg[ks]      = *(const short8*)(wb + ks * 512);
          wreg[17 + ks] = *(const short8*)(wb + nstr + ks * 512);
        }
      }
      const float* b1 = (i == 0) ? A.b1e : A.b1d;
      b1v0 = b1[bid * 32 + col];
      b1v1 = b1[bid * 32 + 16 + col];
    }

    // ---- X0 prefetch (wave0 only; no flag dependency) ----
    f32x4 xv[4] = {{0,0,0,0},{0,0,0,0},{0,0,0,0},{0,0,0,0}};
    if (w == 0 && i < 128) {
      const float* X0 = (i >> 6) ? A.X0d : A.X0e;
      const int t0 = i & 63;
      const float* xb = X0 + (size_t)t0 * GP * 32 + (size_t)bid * 1024;
#pragma unroll
      for (int mt = 0; mt < 2; ++mt)
#pragma unroll
        for (int nt = 0; nt < 2; ++nt)
          xv[mt * 2 + nt] = *(const f32x4*)(xb + (nt * 16 + col) * 32 + mt * 16 + q * 4);
    }

    // ---- stage h[rp] (both layers) into LDS: linear coalesced bypass burst ----
    {
      const char* gsrc = (const char*)A.hst + (size_t)rp * 70656 + tid * 16;
      short8 tmp[17]; short8 tl8;
#pragma unroll
      for (int j = 0; j < 17; ++j)
        asm volatile("global_load_dwordx4 %0, %1, off sc0 sc1"
                     : "=v"(tmp[j]) : "v"(gsrc + j * 4096) : "memory");
      if (w == 3)
        asm volatile("global_load_dwordx4 %0, %1, off sc0 sc1"
                     : "=v"(tl8)
                     : "v"((const char*)A.hst + (size_t)rp * 70656 + (4352 + lane) * 16)
                     : "memory");
      asm volatile("s_waitcnt vmcnt(0)" ::: "memory");
      __builtin_amdgcn_sched_barrier(0);
      short* hw = (short*)hs + tid * 8;
#pragma unroll
      for (int j = 0; j < 17; ++j) *(short8*)(hw + j * 2048) = tmp[j];
      if (w == 3) *(short8*)((short*)hs + (4352 + lane) * 8) = tl8;
    }
    __syncthreads();

    // ---- one product per wave, 4 tiles each, weights from registers ----
    f32x4 a00 = {0,0,0,0}, a01 = {0,0,0,0}, a10 = {0,0,0,0}, a11 = {0,0,0,0};
    if (w < 3) {
#pragma unroll
      for (int ks = 0; ks < 17; ++ks) {
        short8 aA = *(const short8*)(arow + aoff0 + ks * 32);
        short8 aB = *(const short8*)(arow + aoff1 + ks * 32);
        a00 = __builtin_amdgcn_mfma_f32_16x16x32_bf16(aA, wreg[ks],      a00, 0, 0, 0);
        a01 = __builtin_amdgcn_mfma_f32_16x16x32_bf16(aA, wreg[17 + ks], a01, 0, 0, 0);
        a10 = __builtin_amdgcn_mfma_f32_16x16x32_bf16(aB, wreg[ks],      a10, 0, 0, 0);
        a11 = __builtin_amdgcn_mfma_f32_16x16x32_bf16(aB, wreg[17 + ks], a11, 0, 0, 0);
      }
    }
    if (w == 0) {
#pragma unroll
      for (int r = 0; r < 4; ++r) {
        gbuf0[q * 4 + r     ][col]      = a00[r] + xv[0][r];
        gbuf0[q * 4 + r     ][16 + col] = a01[r] + xv[1][r];
        gbuf0[16 + q * 4 + r][col]      = a10[r] + xv[2][r];
        gbuf0[16 + q * 4 + r][16 + col] = a11[r] + xv[3][r];
      }
    } else if (w == 1) {
#pragma unroll
      for (int r = 0; r < 4; ++r) {
        gbuf1a[q * 4 + r     ][col]      = a00[r] + b1v0;
        gbuf1a[q * 4 + r     ][16 + col] = a01[r] + b1v1;
        gbuf1a[16 + q * 4 + r][col]      = a10[r] + b1v0;
        gbuf1a[16 + q * 4 + r][16 + col] = a11[r] + b1v1;
      }
    } else if (w == 2) {
#pragma unroll
      for (int r = 0; r < 4; ++r) {
        gbuf1b[q * 4 + r     ][col]      = a00[r];
        gbuf1b[q * 4 + r     ][16 + col] = a01[r];
        gbuf1b[16 + q * 4 + r][col]      = a10[r];
        gbuf1b[16 + q * 4 + r][16 + col] = a11[r];
      }
    }
    __syncthreads();

    // ---- cell updates: L0 on tid<128 (t=i), L1 on tid>=128 (t=i-1) ----
    if (tid < 128) {
      if (i < 128) {
        unsigned hv = 0;
#pragma unroll
        for (int s = 0; s < 2; ++s) {
          int base = up * 8 + s * 4;
          float gi = gbuf0[cb][base + 0], gf = gbuf0[cb][base + 1];
          float gg = gbuf0[cb][base + 2], go = gbuf0[cb][base + 3];
          float c = c0[cb][up * 2 + s];
          float cn = sigm(gf) * c + sigm(gi) * tanh_(gg);
          float hn = sigm(go) * tanh_(cn);
          c0[cb][up * 2 + s] = cn;
          hv |= ((unsigned)(unsigned short)f2bf(hn)) << (16 * s);
        }
        __hip_atomic_store((unsigned*)A.hst + wp * 17664 + cb * 276 + bid * 4 + up, hv,
                           __ATOMIC_RELAXED, __HIP_MEMORY_SCOPE_AGENT);
      }
    } else {
      if (i >= 1) {
        const int i1 = i - 1;
        unsigned hv = 0;
#pragma unroll
        for (int s = 0; s < 2; ++s) {
          int base = up * 8 + s * 4;
          float gi = gbuf1a[cb][base + 0] + gbuf1b[cb][base + 0];
          float gf = gbuf1a[cb][base + 1] + gbuf1b[cb][base + 1];
          float gg = gbuf1a[cb][base + 2] + gbuf1b[cb][base + 2];
          float go = gbuf1a[cb][base + 3] + gbuf1b[cb][base + 3];
          float c = c1[cb][up * 2 + s];
          float cn = sigm(gf) * c + sigm(gi) * tanh_(gg);
          float hn = sigm(go) * tanh_(cn);
          c1[cb][up * 2 + s] = cn;
          hv |= ((unsigned)(unsigned short)f2bf(hn)) << (16 * s);
        }
        __hip_atomic_store((unsigned*)A.hst + wp * 17664 + 8832 + cb * 276 + bid * 4 + up, hv,
                           __ATOMIC_RELAXED, __HIP_MEMORY_SCOPE_AGENT);
        if (i1 >= 64)
          *((unsigned*)A.H1P + (size_t)((i1 - 64) * SB + cb) * 272 + bid * 4 + up) = hv;
      }
    }

    // ---- flag-array barrier (round-0 proven) ----
    if (i < 128) {
      asm volatile("s_waitcnt vmcnt(0)" ::: "memory");
      __syncthreads();
      if (tid == 0)
        __hip_atomic_store(A.bar + bid * 16, (unsigned)(i + 1),
                           __ATOMIC_RELAXED, __HIP_MEMORY_SCOPE_AGENT);
      if (tid < 64) {
        const unsigned tgt = (unsigned)(i + 1);
        unsigned* p1 = A.bar + lane * 16;
        unsigned* p2 = A.bar + (lane + 1) * 16;
        while (true) {
          unsigned a = __hip_atomic_load(p1, __ATOMIC_RELAXED, __HIP_MEMORY_SCOPE_AGENT);
          unsigned b = __hip_atomic_load(p2, __ATOMIC_RELAXED, __HIP_MEMORY_SCOPE_AGENT);
          if (__all((a >= tgt) && (b >= tgt))) break;
        }
      }
      __syncthreads();
    }
  }
}

// ---------------- projection GEMM + streamed sum-exp ----------------
__global__ void __launch_bounds__(256) k_project(const short* __restrict__ H1P,
                                                 const short* __restrict__ WoutP,
                                                 const float* __restrict__ bout,
                                                 float* __restrict__ partials) {
  int bM = blockIdx.x, bN = blockIdx.y;
  int tid = threadIdx.x, w = tid >> 6, lane = tid & 63, q = lane >> 4, col = lane & 15;
  int wm = w >> 1, wn = w & 1;
  __shared__ __align__(16) short As[128 * 32];
  __shared__ __align__(16) short Bs[128 * 32];
  __shared__ float sred[128][2];
  f32x4 acc[4][4];
#pragma unroll
  for (int mi = 0; mi < 4; ++mi)
#pragma unroll
    for (int ni = 0; ni < 4; ++ni) acc[mi][ni] = (f32x4){0.f, 0.f, 0.f, 0.f};

  for (int ks = 0; ks < 17; ++ks) {
#pragma unroll
    for (int i = 0; i < 2; ++i) {
      int chunk = tid * 2 + i;               // 0..511
      int row = chunk >> 2, ch = chunk & 3;
      ((short8*)As)[chunk] = *(const short8*)(H1P  + (size_t)(bM * 128 + row) * KH + ks * 32 + ch * 8);
      ((short8*)Bs)[chunk] = *(const short8*)(WoutP + (size_t)(bN * 128 + row) * KH + ks * 32 + ch * 8);
    }
    __syncthreads();
    short8 af[4], bf[4];
#pragma unroll
    for (int mi = 0; mi < 4; ++mi) af[mi] = *(const short8*)(As + (wm * 64 + mi * 16 + col) * 32 + q * 8);
#pragma unroll
    for (int ni = 0; ni < 4; ++ni) bf[ni] = *(const short8*)(Bs + (wn * 64 + ni * 16 + col) * 32 + q * 8);
#pragma unroll
    for (int mi = 0; mi < 4; ++mi)
#pragma unroll
      for (int ni = 0; ni < 4; ++ni)
        acc[mi][ni] = __builtin_amdgcn_mfma_f32_16x16x32_bf16(af[mi], bf[ni], acc[mi][ni], 0, 0, 0);
    __syncthreads();
  }
  float bias[4];
#pragma unroll
  for (int ni = 0; ni < 4; ++ni) bias[ni] = bout[bN * 128 + wn * 64 + ni * 16 + col];
#pragma unroll
  for (int mi = 0; mi < 4; ++mi) {
#pragma unroll
    for (int r = 0; r < 4; ++r) {
      float s = 0.f;
#pragma unroll
      for (int ni = 0; ni < 4; ++ni) s += __expf(acc[mi][ni][r] + bias[ni]);
      s += __shfl_xor(s, 1, 64); s += __shfl_xor(s, 2, 64);
      s += __shfl_xor(s, 4, 64); s += __shfl_xor(s, 8, 64);
      if (col == 0) sred[wm * 64 + mi * 16 + q * 4 + r][wn] = s;
    }
  }
  __syncthreads();
  if (tid < 128)
    partials[(size_t)(bM * 128 + tid) * NBN + bN] = sred[tid][0] + sred[tid][1];
}

// ---------------- finish: lse + target logit + loss ----------------
__global__ void __launch_bounds__(256) k_finish(const float* __restrict__ partials,
                                                const short* __restrict__ H1P,
                                                const float* __restrict__ Wout,
                                                const float* __restrict__ bout,
                                                const int* __restrict__ y,
                                                float* __restrict__ out) {
  int tid = threadIdx.x, w = tid >> 6, lane = tid & 63;
  int row = blockIdx.x * 4 + w;           // 0..2047 (t*32+b)
  float s = 0.f;
  for (int j = lane; j < NBN; j += 64) s += partials[(size_t)row * NBN + j];
#pragma unroll
  for (int off = 32; off > 0; off >>= 1) s += __shfl_down(s, off, 64);
  int tok = y[row + 32];                  // y[(t+1)*32 + b]
  float d = 0.f;
  for (int k = lane; k < H; k += 64)
    d += bf2f(H1P[(size_t)row * KH + k]) * Wout[(size_t)tok * H + k];
#pragma unroll
  for (int off = 32; off > 0; off >>= 1) d += __shfl_down(d, off, 64);
  __shared__ float bsum[4];
  if (lane == 0) bsum[w] = __logf(s) - (d + bout[tok]);
  __syncthreads();
  if (tid == 0) atomicAdd(out, (bsum[0] + bsum[1] + bsum[2] + bsum[3]) * (1.f / 32.f));
}

// ---------------- host ----------------
extern "C" void kernel_launch(void* const* d_in, const int* in_sizes, int n_in,
                              void* d_out, int out_size, void* d_ws, size_t ws_size,
                              hipStream_t stream) {
  const int*   x      = (const int*)d_in[0];
  const int*   y      = (const int*)d_in[1];
  const float* encemb = (const float*)d_in[2];
  const float* decemb = (const float*)d_in[3];
  const float* eWih0  = (const float*)d_in[4];
  const float* eWhh0  = (const float*)d_in[5];
  const float* ebih0  = (const float*)d_in[6];
  const float* ebhh0  = (const float*)d_in[7];
  const float* eWih1  = (const float*)d_in[8];
  const float* eWhh1  = (const float*)d_in[9];
  const float* ebih1  = (const float*)d_in[10];
  const float* ebhh1  = (const float*)d_in[11];
  const float* dWih0  = (const float*)d_in[12];
  const float* dWhh0  = (const float*)d_in[13];
  const float* dbih0  = (const float*)d_in[14];
  const float* dbhh0  = (const float*)d_in[15];
  const float* dWih1  = (const float*)d_in[16];
  const float* dWhh1  = (const float*)d_in[17];
  const float* dbih1  = (const float*)d_in[18];
  const float* dbhh1  = (const float*)d_in[19];
  const float* Wout   = (const float*)d_in[20];
  const float* bout   = (const float*)d_in[21];
  float* out = (float*)d_out;

  char* wsb = (char*)d_ws;
  size_t off = 0;
  auto alloc = [&](size_t bytes) -> void* {
    void* p = wsb + off;
    off += (bytes + 255) & ~(size_t)255;
    return p;
  };
  short* WoutP = (short*)alloc((size_t)V * KH * 2);
  short* WAe   = (short*)alloc((size_t)NB * 17408 * 2);
  short* WBe   = (short*)alloc((size_t)NB * 34816 * 2);
  short* WAd   = (short*)alloc((size_t)NB * 17408 * 2);
  short* WBd   = (short*)alloc((size_t)NB * 34816 * 2);
  short* WihPe = (short*)alloc((size_t)GP * KE * 2);
  short* WihPd = (short*)alloc((size_t)GP * KE * 2);
  float* b0e   = (float*)alloc(GP * 4);
  float* b1e   = (float*)alloc(GP * 4);
  float* b0d   = (float*)alloc(GP * 4);
  float* b1d   = (float*)alloc(GP * 4);
  float* X0e   = (float*)alloc((size_t)SEQ * GP * SB * 4);
  float* X0d   = (float*)alloc((size_t)SEQ * GP * SB * 4);
  short* hst   = (short*)alloc((size_t)2 * 2 * 32 * HR * 2);  // [parity][layer][32][552]
  short* H1P   = (short*)alloc((size_t)MROW * KH * 2);
  float* parts = (float*)alloc((size_t)MROW * NBN * 4);
  unsigned* bar = (unsigned*)alloc(NB * 64);

  hipMemsetAsync(d_out, 0, sizeof(float), stream);
  hipMemsetAsync(hst, 0, (size_t)2 * 2 * 32 * HR * 2, stream);
  hipMemsetAsync(bar, 0, NB * 64, stream);

  k_pack_bias<<<(GP + 255) / 256, 256, 0, stream>>>(ebih0, ebhh0, ebih1, ebhh1,
                                                    dbih0, dbhh0, dbih1, dbhh1,
                                                    b0e, b1e, b0d, b1d);
  k_pack_wih<<<(GP * KE / 8 + 255) / 256, 256, 0, stream>>>(eWih0, WihPe);
  k_pack_wih<<<(GP * KE / 8 + 255) / 256, 256, 0, stream>>>(dWih0, WihPd);
  {
    int totA = NB * 2 * 17 * 64, totB = NB * 2 * 34 * 64;
    k_pack_gates<<<(totA + 255) / 256, 256, 0, stream>>>(eWhh0, eWhh0, WAe, 17);
    k_pack_gates<<<(totB + 255) / 256, 256, 0, stream>>>(eWih1, eWhh1, WBe, 34);
    k_pack_gates<<<(totA + 255) / 256, 256, 0, stream>>>(dWhh0, dWhh0, WAd, 17);
    k_pack_gates<<<(totB + 255) / 256, 256, 0, stream>>>(dWih1, dWhh1, WBd, 34);
  }
  k_pack_wout<<<(V * (KH / 8) + 255) / 256, 256, 0, stream>>>(Wout, WoutP);

  k_embproj<<<dim3(GP / 16, 32), 256, 0, stream>>>(WihPe, encemb, x, b0e, X0e);
  k_embproj<<<dim3(GP / 16, 32), 256, 0, stream>>>(WihPd, decemb, y, b0d, X0d);

  RecArgs ra{WAe, WBe, WAd, WBd, X0e, X0d, b1e, b1d, hst, H1P, bar};
  void* kargs[] = {&ra};
  hipLaunchCooperativeKernel((const void*)k_recur, dim3(NB), dim3(256), kargs, 0, stream);

  k_project<<<dim3(MROW / 128, NBN), 256, 0, stream>>>(H1P, WoutP, bout, parts);
  k_finish<<<MROW / 4, 256, 0, stream>>>(parts, H1P, Wout, bout, y, out);
}

// Round 4
// 961.096 us; speedup vs baseline: 1.4619x; 1.1295x over previous
//
#include <hip/hip_runtime.h>

typedef __attribute__((ext_vector_type(8))) short short8;
typedef __attribute__((ext_vector_type(4))) float f32x4;
typedef __attribute__((ext_vector_type(4))) unsigned u32x4;
typedef unsigned long long ull;

constexpr int H    = 516;    // hidden
constexpr int GP   = 2080;   // padded gate cols (65*32), permuted chat = 4*u+g
constexpr int KH   = 544;    // padded hidden K (17*32)
constexpr int KE   = 256;    // embedding dim
constexpr int NB   = 65;     // recurrence blocks (8 units each -> 520 padded units)
constexpr int SB   = 32;     // batch
constexpr int SEQ  = 64;
constexpr int MROW = 2048;   // SEQ*SB
constexpr int V    = 32000;
constexpr int NBN  = 250;    // V/128
// hst layout (producer-major): [parity][layer][slice b<68][row<32] 16B entries
//   slice b holds units b*8..b*8+7 (bf16) for all 32 batch rows.
//   parity stride 69632B, layer stride 34816B, slice 512B, row 16B.

__device__ __forceinline__ float bf2f(short s) {
  unsigned u = ((unsigned)(unsigned short)s) << 16;
  float f; __builtin_memcpy(&f, &u, 4); return f;
}
__device__ __forceinline__ short f2bf(float f) {
  unsigned u; __builtin_memcpy(&u, &f, 4);
  u += 0x7fffu + ((u >> 16) & 1u);
  return (short)(u >> 16);
}
__device__ __forceinline__ float sigm(float x){ return 1.f/(1.f+__expf(-x)); }
__device__ __forceinline__ float tanh_(float x){ float e=__expf(-2.f*x); return (1.f-e)/(1.f+e); }

// ---------------- pack kernels ----------------
__global__ void k_pack_gates(const float* __restrict__ W1, const float* __restrict__ W2,
                             short* __restrict__ dst, int ksteps) {
  int gid = blockIdx.x * 256 + threadIdx.x;
  int total = NB * 2 * ksteps * 64;
  if (gid >= total) return;
  int lane = gid & 63;
  int rest = gid >> 6;
  int ks = rest % ksteps; rest /= ksteps;
  int nt = rest & 1; int bid = rest >> 1;
  int chat = bid * 32 + nt * 16 + (lane & 15);
  int u = chat >> 2, g = chat & 3;
  int kb = ks * 32 + (lane >> 4) * 8;
  short8 v;
#pragma unroll
  for (int j = 0; j < 8; ++j) {
    int k = kb + j;
    const float* src = W1; int kk = k;
    if (k >= KH) { src = W2; kk = k - KH; }
    float f = 0.f;
    if (u < H && kk < H) f = src[(size_t)(g * H + u) * H + kk];
    v[j] = f2bf(f);
  }
  *(short8*)(dst + (size_t)gid * 8) = v;
}

__global__ void k_pack_wout(const float* __restrict__ Wout, short* __restrict__ dst) {
  int gid = blockIdx.x * 256 + threadIdx.x;          // group of 8
  if (gid >= V * (KH / 8)) return;
  int row = gid / (KH / 8);
  int kb = (gid % (KH / 8)) * 8;
  short8 v;
#pragma unroll
  for (int j = 0; j < 8; ++j) {
    int k = kb + j;
    v[j] = f2bf(k < H ? Wout[(size_t)row * H + k] : 0.f);
  }
  *(short8*)(dst + (size_t)gid * 8) = v;
}

__global__ void k_pack_wih(const float* __restrict__ Wih0, short* __restrict__ dst) {
  int gid = blockIdx.x * 256 + threadIdx.x;          // group of 8
  if (gid >= GP * (KE / 8)) return;
  int chat = gid / (KE / 8);
  int kb = (gid % (KE / 8)) * 8;
  int u = chat >> 2, g = chat & 3;
  short8 v;
#pragma unroll
  for (int j = 0; j < 8; ++j)
    v[j] = f2bf(u < H ? Wih0[(size_t)(g * H + u) * KE + kb + j] : 0.f);
  *(short8*)(dst + (size_t)gid * 8) = v;
}

__global__ void k_pack_bias(const float* ebih0, const float* ebhh0, const float* ebih1, const float* ebhh1,
                            const float* dbih0, const float* dbhh0, const float* dbih1, const float* dbhh1,
                            float* b0e, float* b1e, float* b0d, float* b1d) {
  int chat = blockIdx.x * 256 + threadIdx.x;
  if (chat >= GP) return;
  int u = chat >> 2, g = chat & 3, n = g * H + u;
  bool ok = (u < H);
  b0e[chat] = ok ? ebih0[n] + ebhh0[n] : 0.f;
  b1e[chat] = ok ? ebih1[n] + ebhh1[n] : 0.f;
  b0d[chat] = ok ? dbih0[n] + dbhh0[n] : 0.f;
  b1d[chat] = ok ? dbih1[n] + dbhh1[n] : 0.f;
}

// ---------------- batched input projection ----------------
__global__ void __launch_bounds__(256) k_embproj(const short* __restrict__ WihP,
                                                 const float* __restrict__ emb,
                                                 const int* __restrict__ toks,
                                                 const float* __restrict__ b0P,
                                                 float* __restrict__ X0P) {
  int tid = threadIdx.x, w = tid >> 6, lane = tid & 63, q = lane >> 4, col = lane & 15;
  int mt = blockIdx.x;                 // 0..129
  int ntile = blockIdx.y * 4 + w;      // 0..127
  int tb = ntile * 16 + col;
  int tok = toks[tb];
  const short* Ap = WihP + (size_t)(mt * 16 + col) * KE + q * 8;
  const float* Bp = emb + (size_t)tok * KE + q * 8;
  f32x4 acc = {0.f, 0.f, 0.f, 0.f};
#pragma unroll
  for (int ks = 0; ks < 8; ++ks) {
    short8 a = *(const short8*)(Ap + ks * 32);
    const f32x4* b4 = (const f32x4*)(Bp + ks * 32);
    f32x4 b0v = b4[0], b1v = b4[1];
    short8 bb;
    bb[0]=f2bf(b0v[0]); bb[1]=f2bf(b0v[1]); bb[2]=f2bf(b0v[2]); bb[3]=f2bf(b0v[3]);
    bb[4]=f2bf(b1v[0]); bb[5]=f2bf(b1v[1]); bb[6]=f2bf(b1v[2]); bb[7]=f2bf(b1v[3]);
    acc = __builtin_amdgcn_mfma_f32_16x16x32_bf16(a, bb, acc, 0, 0, 0);
  }
  int chat0 = mt * 16 + q * 4;
  f32x4 bias = *(const f32x4*)(b0P + chat0);
  int t = tb >> 5, b = tb & 31;
  float* dst = X0P + ((size_t)t * GP) * 32 + b;
#pragma unroll
  for (int r = 0; r < 4; ++r)
    dst[(size_t)(chat0 + r) * 32] = acc[r] + bias[r];
}

// ---------------- async-stream GEMM helpers ----------------
#define WL(dst, addr) asm volatile("global_load_dwordx4 %0, %1, off" : "=&v"(dst) : "v"(addr))
#define SW0 do { __builtin_amdgcn_s_waitcnt(0x0F70); __builtin_amdgcn_sched_barrier(0); } while (0)

template <int N>
__device__ __forceinline__ void vmwait() {
  __builtin_amdgcn_s_waitcnt((N & 15) | (0x7 << 4) | (0xF << 8) | ((N >> 4) << 14));
  __builtin_amdgcn_sched_barrier(0);
}

// segment 1: TWO products per pair (P0 -> p-set, P1 -> q-set)
template <int NPT, int NP1, int P>
__device__ __forceinline__ void phase1(short8 (&fA)[NPT], short8 (&fB)[NPT], const short8 (&wr)[28],
                                       f32x4& p00, f32x4& p01, f32x4& p10, f32x4& p11,
                                       f32x4& q00, f32x4& q01, f32x4& q10, f32x4& q11) {
  if constexpr (P < NP1) {
    vmwait<2 * (NPT - 1 - P)>();
    p00 = __builtin_amdgcn_mfma_f32_16x16x32_bf16(fA[P], wr[4*P+0], p00, 0, 0, 0);
    p01 = __builtin_amdgcn_mfma_f32_16x16x32_bf16(fA[P], wr[4*P+1], p01, 0, 0, 0);
    p10 = __builtin_amdgcn_mfma_f32_16x16x32_bf16(fB[P], wr[4*P+0], p10, 0, 0, 0);
    p11 = __builtin_amdgcn_mfma_f32_16x16x32_bf16(fB[P], wr[4*P+1], p11, 0, 0, 0);
    q00 = __builtin_amdgcn_mfma_f32_16x16x32_bf16(fA[P], wr[4*P+2], q00, 0, 0, 0);
    q01 = __builtin_amdgcn_mfma_f32_16x16x32_bf16(fA[P], wr[4*P+3], q01, 0, 0, 0);
    q10 = __builtin_amdgcn_mfma_f32_16x16x32_bf16(fB[P], wr[4*P+2], q10, 0, 0, 0);
    q11 = __builtin_amdgcn_mfma_f32_16x16x32_bf16(fB[P], wr[4*P+3], q11, 0, 0, 0);
    phase1<NPT, NP1, P + 1>(fA, fB, wr, p00, p01, p10, p11, q00, q01, q10, q11);
  }
}

// segment 2: ONE product per pair (P2 -> q-set), weights at wr[4*NP1 + 2*P]
template <int NPT, int NP1, int P>
__device__ __forceinline__ void phase2(short8 (&fA)[NPT], short8 (&fB)[NPT], const short8 (&wr)[28],
                                       f32x4& q00, f32x4& q01, f32x4& q10, f32x4& q11) {
  if constexpr (NP1 + P < NPT) {
    vmwait<2 * (NPT - NP1 - 1 - P)>();
    q00 = __builtin_amdgcn_mfma_f32_16x16x32_bf16(fA[NP1+P], wr[4*NP1 + 2*P + 0], q00, 0, 0, 0);
    q01 = __builtin_amdgcn_mfma_f32_16x16x32_bf16(fA[NP1+P], wr[4*NP1 + 2*P + 1], q01, 0, 0, 0);
    q10 = __builtin_amdgcn_mfma_f32_16x16x32_bf16(fB[NP1+P], wr[4*NP1 + 2*P + 0], q10, 0, 0, 0);
    q11 = __builtin_amdgcn_mfma_f32_16x16x32_bf16(fB[NP1+P], wr[4*NP1 + 2*P + 1], q11, 0, 0, 0);
    phase2<NPT, NP1, P + 1>(fA, fB, wr, q00, q01, q10, q11);
  }
}

// issue all NPT fragment-pairs (bypass, MALL-coherent), then counted-vmcnt MFMA stream
template <int NPT, int NP1>
__device__ __forceinline__ void run_gemm(u32x4 sr1, int sb1, u32x4 sr2, int sb2, int voff,
                                         const short8 (&wr)[28],
                                         f32x4& p00, f32x4& p01, f32x4& p10, f32x4& p11,
                                         f32x4& q00, f32x4& q01, f32x4& q10, f32x4& q11) {
  short8 fA[NPT], fB[NPT];
#pragma unroll
  for (int p = 0; p < NP1; ++p)
    asm volatile("buffer_load_dwordx4 %0, %2, %3, %4 offen sc0 sc1\n\t"
                 "buffer_load_dwordx4 %1, %2, %3, %4 offen offset:256 sc0 sc1"
                 : "=&v"(fA[p]), "=&v"(fB[p])
                 : "v"(voff), "s"(sr1), "s"(sb1 + p * 2048));
#pragma unroll
  for (int p = NP1; p < NPT; ++p)
    asm volatile("buffer_load_dwordx4 %0, %2, %3, %4 offen sc0 sc1\n\t"
                 "buffer_load_dwordx4 %1, %2, %3, %4 offen offset:256 sc0 sc1"
                 : "=&v"(fA[p]), "=&v"(fB[p])
                 : "v"(voff), "s"(sr2), "s"(sb2 + (p - NP1) * 2048));
  phase1<NPT, NP1, 0>(fA, fB, wr, p00, p01, p10, p11, q00, q01, q10, q11);
  phase2<NPT, NP1, 0>(fA, fB, wr, q00, q01, q10, q11);
}

// ---------------- cooperative recurrence ----------------
// Round-3 sync skeleton (single flag/block/iter, proven). h-dataflow rebuilt:
// NO LDS h-staging. hst is producer-major; each lane buffer_loads its MFMA
// A-fragments directly from MALL (sc0 sc1), all pairs issued upfront, consumed
// via counted vmcnt -> load stream overlaps MFMA. Dup-free k-job split:
//   w0: L0 ks0-5  (P0->p, P1->q)      w1: L0 ks6-12 (P0->p, P1->q)
//   w2: L0 ks13-16 (P0,P1) + L1 ks0-4 (P2->q)
//   w3: L1 ks5-16 (P2->q)
// Partial sums merged in cell phase: L0 = g0a+g0b+g0c + X0; L1 = g1a..g1d + b1.
// All GEMM-path loads are inline asm so compiler waitcnt insertion never
// drains the pipeline. Weights register-resident (reload at i==64/65).
struct RecArgs {
  const short *WAe, *WBe, *WAd, *WBd;
  const float *X0e, *X0d, *b1e, *b1d;
  short *hst, *H1P;
  unsigned *bar;            // 65 flags, stride 16 u32 (64B)
};

__global__ void __launch_bounds__(256, 1) k_recur(RecArgs A) {
  const int tid = threadIdx.x, lane = tid & 63, w = tid >> 6;
  const int q = lane >> 4, col = lane & 15;
  const int bid = blockIdx.x;
  __shared__ float g0a[32][33], g0b[32][33], g0c[32][33];
  __shared__ float g1a[32][33], g1b[32][33], g1c[32][33], g1d[32][33];
  __shared__ float c0[32][8], c1[32][8];
  const int tl = tid & 127, cb = tl >> 2, up = tl & 3;
  if (tid < 128) { c0[cb][up * 2] = 0.f; c0[cb][up * 2 + 1] = 0.f; }
  else           { c1[cb][up * 2] = 0.f; c1[cb][up * 2 + 1] = 0.f; }

  float (*gp0)[33] = (w == 0) ? g0a : (w == 1) ? g0b : g0c;
  float (*gp1)[33] = (w == 0) ? g1a : (w == 1) ? g1b : (w == 2) ? g1c : g1d;

  const int voff = q * 512 + col * 16;
  short8 wr[28];
  float b1r[8];

  for (int i = 0; i <= 128; ++i) {
    const int rp = (i + 1) & 1, wp = i & 1;

    // ---- phase-boundary weight reloads (asm loads; invisible to compiler vmcnt) ----
    if (i == 0 || i == 64) {           // W0 (P0) fragments
      const short* wa = ((i == 64) ? A.WAd : A.WAe) + (size_t)bid * 17408 + lane * 8;
      if (w == 0) {
#pragma unroll
        for (int j = 0; j < 6; ++j) { WL(wr[4*j], wa + j*512); WL(wr[4*j+1], wa + 8704 + j*512); }
      } else if (w == 1) {
#pragma unroll
        for (int j = 0; j < 7; ++j) { WL(wr[4*j], wa + (6+j)*512); WL(wr[4*j+1], wa + 8704 + (6+j)*512); }
      } else if (w == 2) {
#pragma unroll
        for (int j = 0; j < 4; ++j) { WL(wr[4*j], wa + (13+j)*512); WL(wr[4*j+1], wa + 8704 + (13+j)*512); }
      }
      SW0;
    }
    if (i == 0 || i == 65) {           // W1 (P1) + W2 (P2) fragments + b1
      const short* wb = ((i == 65) ? A.WBd : A.WBe) + (size_t)bid * 34816 + lane * 8;
      if (w == 0) {
#pragma unroll
        for (int j = 0; j < 6; ++j) { WL(wr[4*j+2], wb + j*512); WL(wr[4*j+3], wb + 17408 + j*512); }
      } else if (w == 1) {
#pragma unroll
        for (int j = 0; j < 7; ++j) { WL(wr[4*j+2], wb + (6+j)*512); WL(wr[4*j+3], wb + 17408 + (6+j)*512); }
      } else if (w == 2) {
#pragma unroll
        for (int j = 0; j < 4; ++j) { WL(wr[4*j+2], wb + (13+j)*512); WL(wr[4*j+3], wb + 17408 + (13+j)*512); }
#pragma unroll
        for (int j = 0; j < 5; ++j) { WL(wr[16+2*j], wb + (17+j)*512); WL(wr[16+2*j+1], wb + 17408 + (17+j)*512); }
      } else {
#pragma unroll
        for (int j = 0; j < 12; ++j) { WL(wr[2*j], wb + (22+j)*512); WL(wr[2*j+1], wb + 17408 + (22+j)*512); }
      }
      SW0;
      if (tid >= 128) {
        const float* b1p = (i == 65) ? A.b1d : A.b1e;
#pragma unroll
        for (int j = 0; j < 8; ++j) b1r[j] = b1p[bid * 32 + up * 8 + j];
      }
    }

    // ---- X0 prefetch for L0 cells (plain cached loads; no flag dependency) ----
    float x0r[8];
    if (tid < 128) {
      const float* X0 = (i >> 6) ? A.X0d : A.X0e;
      const float* xp = X0 + ((size_t)(i & 63) * GP + bid * 32 + up * 8) * 32 + cb;
#pragma unroll
      for (int j = 0; j < 8; ++j) x0r[j] = xp[j * 32];
    }

    // ---- SRSRC descriptors for this parity ----
    ull ba = (ull)(size_t)A.hst + (size_t)rp * 69632u;
    u32x4 sr0 = {(unsigned)ba, (unsigned)(ba >> 32), 0xffffffffu, 0x00020000u};
    ull bb2 = ba + 34816u;
    u32x4 sr1 = {(unsigned)bb2, (unsigned)(bb2 >> 32), 0xffffffffu, 0x00020000u};

    // ---- per-wave streamed GEMM (fragments straight from MALL) ----
    f32x4 p00 = {0.f,0.f,0.f,0.f}, p01 = p00, p10 = p00, p11 = p00;
    f32x4 q00 = p00, q01 = p00, q10 = p00, q11 = p00;
    if (w == 0)      run_gemm<6, 6>(sr0, 0,     sr0, 0,     voff, wr, p00,p01,p10,p11, q00,q01,q10,q11);
    else if (w == 1) run_gemm<7, 7>(sr0, 12288, sr0, 0,     voff, wr, p00,p01,p10,p11, q00,q01,q10,q11);
    else if (w == 2) run_gemm<9, 4>(sr0, 26624, sr1, 0,     voff, wr, p00,p01,p10,p11, q00,q01,q10,q11);
    else             run_gemm<12, 0>(sr0, 0,    sr1, 10240, voff, wr, p00,p01,p10,p11, q00,q01,q10,q11);

    // ---- partial-sum buffers ----
#pragma unroll
    for (int r = 0; r < 4; ++r) {
      if (w < 3) {
        gp0[q * 4 + r][col] = p00[r];      gp0[q * 4 + r][16 + col] = p01[r];
        gp0[16 + q * 4 + r][col] = p10[r]; gp0[16 + q * 4 + r][16 + col] = p11[r];
      }
      gp1[q * 4 + r][col] = q00[r];      gp1[q * 4 + r][16 + col] = q01[r];
      gp1[16 + q * 4 + r][col] = q10[r]; gp1[16 + q * 4 + r][16 + col] = q11[r];
    }
    __syncthreads();

    // ---- cell updates: L0 on tid<128 (t=i), L1 on tid>=128 (t=i-1) ----
    if (tid < 128) {
      if (i < 128) {
        unsigned hv = 0;
#pragma unroll
        for (int s = 0; s < 2; ++s) {
          int base = up * 8 + s * 4;
          float gi = g0a[cb][base+0] + g0b[cb][base+0] + g0c[cb][base+0] + x0r[s*4+0];
          float gf = g0a[cb][base+1] + g0b[cb][base+1] + g0c[cb][base+1] + x0r[s*4+1];
          float gg = g0a[cb][base+2] + g0b[cb][base+2] + g0c[cb][base+2] + x0r[s*4+2];
          float go = g0a[cb][base+3] + g0b[cb][base+3] + g0c[cb][base+3] + x0r[s*4+3];
          float c = c0[cb][up * 2 + s];
          float cn = sigm(gf) * c + sigm(gi) * tanh_(gg);
          float hn = sigm(go) * tanh_(cn);
          c0[cb][up * 2 + s] = cn;
          hv |= ((unsigned)(unsigned short)f2bf(hn)) << (16 * s);
        }
        __hip_atomic_store((unsigned*)A.hst + wp * 17408 + bid * 128 + cb * 4 + up, hv,
                           __ATOMIC_RELAXED, __HIP_MEMORY_SCOPE_AGENT);
      }
    } else {
      if (i >= 1) {
        const int i1 = i - 1;
        unsigned hv = 0;
#pragma unroll
        for (int s = 0; s < 2; ++s) {
          int base = up * 8 + s * 4;
          float gi = g1a[cb][base+0] + g1b[cb][base+0] + g1c[cb][base+0] + g1d[cb][base+0] + b1r[s*4+0];
          float gf = g1a[cb][base+1] + g1b[cb][base+1] + g1c[cb][base+1] + g1d[cb][base+1] + b1r[s*4+1];
          float gg = g1a[cb][base+2] + g1b[cb][base+2] + g1c[cb][base+2] + g1d[cb][base+2] + b1r[s*4+2];
          float go = g1a[cb][base+3] + g1b[cb][base+3] + g1c[cb][base+3] + g1d[cb][base+3] + b1r[s*4+3];
          float c = c1[cb][up * 2 + s];
          float cn = sigm(gf) * c + sigm(gi) * tanh_(gg);
          float hn = sigm(go) * tanh_(cn);
          c1[cb][up * 2 + s] = cn;
          hv |= ((unsigned)(unsigned short)f2bf(hn)) << (16 * s);
        }
        __hip_atomic_store((unsigned*)A.hst + wp * 17408 + 8704 + bid * 128 + cb * 4 + up, hv,
                           __ATOMIC_RELAXED, __HIP_MEMORY_SCOPE_AGENT);
        if (i1 >= 64)
          *((unsigned*)A.H1P + (size_t)((i1 - 64) * SB + cb) * 272 + bid * 4 + up) = hv;
      }
    }

    // ---- flag-array barrier (round-0/3 proven) ----
    if (i < 128) {
      asm volatile("s_waitcnt vmcnt(0)" ::: "memory");
      __syncthreads();
      if (tid == 0)
        __hip_atomic_store(A.bar + bid * 16, (unsigned)(i + 1),
                           __ATOMIC_RELAXED, __HIP_MEMORY_SCOPE_AGENT);
      if (tid < 64) {
        const unsigned tgt = (unsigned)(i + 1);
        unsigned* f1 = A.bar + lane * 16;
        unsigned* f2 = A.bar + (lane + 1) * 16;
        while (true) {
          unsigned a = __hip_atomic_load(f1, __ATOMIC_RELAXED, __HIP_MEMORY_SCOPE_AGENT);
          unsigned b = __hip_atomic_load(f2, __ATOMIC_RELAXED, __HIP_MEMORY_SCOPE_AGENT);
          if (__all((a >= tgt) && (b >= tgt))) break;
        }
      }
      __syncthreads();
    }
  }
}

// ---------------- projection GEMM + streamed sum-exp ----------------
__global__ void __launch_bounds__(256) k_project(const short* __restrict__ H1P,
                                                 const short* __restrict__ WoutP,
                                                 const float* __restrict__ bout,
                                                 float* __restrict__ partials) {
  int bM = blockIdx.x, bN = blockIdx.y;
  int tid = threadIdx.x, w = tid >> 6, lane = tid & 63, q = lane >> 4, col = lane & 15;
  int wm = w >> 1, wn = w & 1;
  __shared__ __align__(16) short As[128 * 32];
  __shared__ __align__(16) short Bs[128 * 32];
  __shared__ float sred[128][2];
  f32x4 acc[4][4];
#pragma unroll
  for (int mi = 0; mi < 4; ++mi)
#pragma unroll
    for (int ni = 0; ni < 4; ++ni) acc[mi][ni] = (f32x4){0.f, 0.f, 0.f, 0.f};

  for (int ks = 0; ks < 17; ++ks) {
#pragma unroll
    for (int i = 0; i < 2; ++i) {
      int chunk = tid * 2 + i;               // 0..511
      int row = chunk >> 2, ch = chunk & 3;
      ((short8*)As)[chunk] = *(const short8*)(H1P  + (size_t)(bM * 128 + row) * KH + ks * 32 + ch * 8);
      ((short8*)Bs)[chunk] = *(const short8*)(WoutP + (size_t)(bN * 128 + row) * KH + ks * 32 + ch * 8);
    }
    __syncthreads();
    short8 af[4], bf[4];
#pragma unroll
    for (int mi = 0; mi < 4; ++mi) af[mi] = *(const short8*)(As + (wm * 64 + mi * 16 + col) * 32 + q * 8);
#pragma unroll
    for (int ni = 0; ni < 4; ++ni) bf[ni] = *(const short8*)(Bs + (wn * 64 + ni * 16 + col) * 32 + q * 8);
#pragma unroll
    for (int mi = 0; mi < 4; ++mi)
#pragma unroll
      for (int ni = 0; ni < 4; ++ni)
        acc[mi][ni] = __builtin_amdgcn_mfma_f32_16x16x32_bf16(af[mi], bf[ni], acc[mi][ni], 0, 0, 0);
    __syncthreads();
  }
  float bias[4];
#pragma unroll
  for (int ni = 0; ni < 4; ++ni) bias[ni] = bout[bN * 128 + wn * 64 + ni * 16 + col];
#pragma unroll
  for (int mi = 0; mi < 4; ++mi) {
#pragma unroll
    for (int r = 0; r < 4; ++r) {
      float s = 0.f;
#pragma unroll
      for (int ni = 0; ni < 4; ++ni) s += __expf(acc[mi][ni][r] + bias[ni]);
      s += __shfl_xor(s, 1, 64); s += __shfl_xor(s, 2, 64);
      s += __shfl_xor(s, 4, 64); s += __shfl_xor(s, 8, 64);
      if (col == 0) sred[wm * 64 + mi * 16 + q * 4 + r][wn] = s;
    }
  }
  __syncthreads();
  if (tid < 128)
    partials[(size_t)(bM * 128 + tid) * NBN + bN] = sred[tid][0] + sred[tid][1];
}

// ---------------- finish: lse + target logit + loss ----------------
__global__ void __launch_bounds__(256) k_finish(const float* __restrict__ partials,
                                                const short* __restrict__ H1P,
                                                const float* __restrict__ Wout,
                                                const float* __restrict__ bout,
                                                const int* __restrict__ y,
                                                float* __restrict__ out) {
  int tid = threadIdx.x, w = tid >> 6, lane = tid & 63;
  int row = blockIdx.x * 4 + w;           // 0..2047 (t*32+b)
  float s = 0.f;
  for (int j = lane; j < NBN; j += 64) s += partials[(size_t)row * NBN + j];
#pragma unroll
  for (int off = 32; off > 0; off >>= 1) s += __shfl_down(s, off, 64);
  int tok = y[row + 32];                  // y[(t+1)*32 + b]
  float d = 0.f;
  for (int k = lane; k < H; k += 64)
    d += bf2f(H1P[(size_t)row * KH + k]) * Wout[(size_t)tok * H + k];
#pragma unroll
  for (int off = 32; off > 0; off >>= 1) d += __shfl_down(d, off, 64);
  __shared__ float bsum[4];
  if (lane == 0) bsum[w] = __logf(s) - (d + bout[tok]);
  __syncthreads();
  if (tid == 0) atomicAdd(out, (bsum[0] + bsum[1] + bsum[2] + bsum[3]) * (1.f / 32.f));
}

// ---------------- host ----------------
extern "C" void kernel_launch(void* const* d_in, const int* in_sizes, int n_in,
                              void* d_out, int out_size, void* d_ws, size_t ws_size,
                              hipStream_t stream) {
  const int*   x      = (const int*)d_in[0];
  const int*   y      = (const int*)d_in[1];
  const float* encemb = (const float*)d_in[2];
  const float* decemb = (const float*)d_in[3];
  const float* eWih0  = (const float*)d_in[4];
  const float* eWhh0  = (const float*)d_in[5];
  const float* ebih0  = (const float*)d_in[6];
  const float* ebhh0  = (const float*)d_in[7];
  const float* eWih1  = (const float*)d_in[8];
  const float* eWhh1  = (const float*)d_in[9];
  const float* ebih1  = (const float*)d_in[10];
  const float* ebhh1  = (const float*)d_in[11];
  const float* dWih0  = (const float*)d_in[12];
  const float* dWhh0  = (const float*)d_in[13];
  const float* dbih0  = (const float*)d_in[14];
  const float* dbhh0  = (const float*)d_in[15];
  const float* dWih1  = (const float*)d_in[16];
  const float* dWhh1  = (const float*)d_in[17];
  const float* dbih1  = (const float*)d_in[18];
  const float* dbhh1  = (const float*)d_in[19];
  const float* Wout   = (const float*)d_in[20];
  const float* bout   = (const float*)d_in[21];
  float* out = (float*)d_out;

  char* wsb = (char*)d_ws;
  size_t off = 0;
  auto alloc = [&](size_t bytes) -> void* {
    void* p = wsb + off;
    off += (bytes + 255) & ~(size_t)255;
    return p;
  };
  short* WoutP = (short*)alloc((size_t)V * KH * 2);
  short* WAe   = (short*)alloc((size_t)NB * 17408 * 2);
  short* WBe   = (short*)alloc((size_t)NB * 34816 * 2);
  short* WAd   = (short*)alloc((size_t)NB * 17408 * 2);
  short* WBd   = (short*)alloc((size_t)NB * 34816 * 2);
  short* WihPe = (short*)alloc((size_t)GP * KE * 2);
  short* WihPd = (short*)alloc((size_t)GP * KE * 2);
  float* b0e   = (float*)alloc(GP * 4);
  float* b1e   = (float*)alloc(GP * 4);
  float* b0d   = (float*)alloc(GP * 4);
  float* b1d   = (float*)alloc(GP * 4);
  float* X0e   = (float*)alloc((size_t)SEQ * GP * SB * 4);
  float* X0d   = (float*)alloc((size_t)SEQ * GP * SB * 4);
  short* hst   = (short*)alloc((size_t)2 * 69632);   // [parity][layer][slice 68][row 32] 16B
  short* H1P   = (short*)alloc((size_t)MROW * KH * 2);
  float* parts = (float*)alloc((size_t)MROW * NBN * 4);
  unsigned* bar = (unsigned*)alloc(NB * 64);

  hipMemsetAsync(d_out, 0, sizeof(float), stream);
  hipMemsetAsync(hst, 0, (size_t)2 * 69632, stream);
  hipMemsetAsync(bar, 0, NB * 64, stream);

  k_pack_bias<<<(GP + 255) / 256, 256, 0, stream>>>(ebih0, ebhh0, ebih1, ebhh1,
                                                    dbih0, dbhh0, dbih1, dbhh1,
                                                    b0e, b1e, b0d, b1d);
  k_pack_wih<<<(GP * KE / 8 + 255) / 256, 256, 0, stream>>>(eWih0, WihPe);
  k_pack_wih<<<(GP * KE / 8 + 255) / 256, 256, 0, stream>>>(dWih0, WihPd);
  {
    int totA = NB * 2 * 17 * 64, totB = NB * 2 * 34 * 64;
    k_pack_gates<<<(totA + 255) / 256, 256, 0, stream>>>(eWhh0, eWhh0, WAe, 17);
    k_pack_gates<<<(totB + 255) / 256, 256, 0, stream>>>(eWih1, eWhh1, WBe, 34);
    k_pack_gates<<<(totA + 255) / 256, 256, 0, stream>>>(dWhh0, dWhh0, WAd, 17);
    k_pack_gates<<<(totB + 255) / 256, 256, 0, stream>>>(dWih1, dWhh1, WBd, 34);
  }
  k_pack_wout<<<(V * (KH / 8) + 255) / 256, 256, 0, stream>>>(Wout, WoutP);

  k_embproj<<<dim3(GP / 16, 32), 256, 0, stream>>>(WihPe, encemb, x, b0e, X0e);
  k_embproj<<<dim3(GP / 16, 32), 256, 0, stream>>>(WihPd, decemb, y, b0d, X0d);

  RecArgs ra{WAe, WBe, WAd, WBd, X0e, X0d, b1e, b1d, hst, H1P, bar};
  void* kargs[] = {&ra};
  hipLaunchCooperativeKernel((const void*)k_recur, dim3(NB), dim3(256), kargs, 0, stream);

  k_project<<<dim3(MROW / 128, NBN), 256, 0, stream>>>(H1P, WoutP, bout, parts);
  k_finish<<<MROW / 4, 256, 0, stream>>>(parts, H1P, Wout, bout, y, out);
}